// Round 10
// baseline (346.077 us; speedup 1.0000x reference)
//
#include <hip/hip_runtime.h>
#include <hip/hip_bf16.h>

// ---------------- types & helpers ----------------

typedef __attribute__((ext_vector_type(8)))  short bf16x8;   // 8 bf16 = 4 VGPR
typedef __attribute__((ext_vector_type(16))) float f32x16;   // MFMA 32x32 acc
typedef unsigned short u16;

__device__ __forceinline__ u16 f2bf(float x) {               // RNE fp32->bf16
  union { float f; unsigned u; } c; c.f = x;
  return (u16)((c.u + 0x7fffu + ((c.u >> 16) & 1u)) >> 16);
}
__device__ __forceinline__ float bf2f(u16 u) {               // exact bf16->fp32
  union { unsigned u; float f; } c; c.u = ((unsigned)u) << 16;
  return c.f;
}

// A-pack addressing (fragment-linear, 64-row m-tiles, 32-k ksteps).
// Element (row r, col k), KSQ = Fi/32:
//   slot = ((r>>6)*KSQ + (k>>5))*4 + ((r>>5)&1)*2 + ((k>>4)&1)
//   lane = (r&31) + ((k>>3)&1)*32 ;  j = k&7 ;  idx = slot*512 + lane*8 + j
__device__ __forceinline__ size_t apidx(int r, int k, int KSQ) {
  const int slot = (((r >> 6) * KSQ + (k >> 5)) << 2) + (((r >> 5) & 1) << 1) + ((k >> 4) & 1);
  return ((size_t)slot << 9) + (size_t)(((((k >> 3) & 1) << 5) | (r & 31)) << 3) + (k & 7);
}

// ---------------- fused init: dtype probes + zero + sentinel ----------------
// block 0: v dtype probe; block 1: ei width probe; blocks [2, 2+zb): zero
// deg/cnt; blocks >= 2+zb: sentinel-fill d_out (overwritten by heads later).
__global__ void k_init(const unsigned* __restrict__ v, int nv, int* __restrict__ vflag,
                       const unsigned* __restrict__ ei, int ne, int* __restrict__ eflag,
                       float* __restrict__ deg, int* __restrict__ cnt, int n, int zb,
                       u16* __restrict__ outSent, int outN) {
  __shared__ unsigned red[256];
  if (blockIdx.x == 0) {
    int ok = 0;
    for (int i = threadIdx.x; i < nv; i += 256) {
      unsigned lo = v[i] & 0xffffu;
      unsigned ef = (lo >> 7) & 0xffu;
      if (ef >= 115u && ef <= 140u) ok++;
    }
    red[threadIdx.x] = (unsigned)ok;
    __syncthreads();
    for (int s = 128; s > 0; s >>= 1) {
      if (threadIdx.x < s) red[threadIdx.x] += red[threadIdx.x + s];
      __syncthreads();
    }
    if (threadIdx.x == 0) *vflag = ((int)red[0] < nv / 2) ? 1 : 0;
  } else if (blockIdx.x == 1) {
    unsigned acc = 0;
    for (int i = threadIdx.x; i < ne; i += 256)
      if (i & 1) acc |= ei[i];
    red[threadIdx.x] = acc;
    __syncthreads();
    for (int s = 128; s > 0; s >>= 1) {
      if (threadIdx.x < s) red[threadIdx.x] |= red[threadIdx.x + s];
      __syncthreads();
    }
    if (threadIdx.x == 0) *eflag = (red[0] == 0u) ? 1 : 0;
  } else if (blockIdx.x < 2 + zb) {
    int i = (blockIdx.x - 2) * 256 + threadIdx.x;
    if (i < n) { deg[i] = 0.0f; cnt[i] = 0; }
  } else {
    int i = (blockIdx.x - 2 - zb) * 256 + threadIdx.x;
    if (i < outN) outSent[i] = 0x3F00;
  }
}

// ---------------- fused pack: 5 weight packs + input convert ----------------
__device__ __forceinline__ void wpack_dev(
    const void* __restrict__ W, int wflag, int K, int Fo,
    u16* __restrict__ dstHi, u16* __restrict__ dstLo, int blk, int tid) {
  const int t = blk * 256 + tid;
  const int KS = K >> 5;
  const int total = (Fo >> 6) * KS * 4;
  const int s = t >> 6;
  if (s >= total) return;
  const int lane = t & 63;
  const int fb = s & 3;
  const int sk = s >> 2;
  const int ks = sk % KS;
  const int nt = sk / KS;
  const int col = (nt << 6) + ((fb >> 1) << 5) + (lane & 31);
  const int row = (ks << 5) + ((fb & 1) << 4) + ((lane >> 5) << 3);
  bf16x8 hi;
  if (wflag) {
    const float* Wf = (const float*)W;
    bf16x8 lo;
#pragma unroll
    for (int j = 0; j < 8; j++) {
      float wv = Wf[(size_t)(row + j) * Fo + col];
      u16 h = f2bf(wv);
      hi[j] = (short)h;
      lo[j] = (short)f2bf(wv - bf2f(h));
    }
    *(bf16x8*)(dstLo + (size_t)s * 512 + lane * 8) = lo;
  } else {
    const u16* Wb = (const u16*)W;
#pragma unroll
    for (int j = 0; j < 8; j++)
      hi[j] = (short)Wb[(size_t)(row + j) * Fo + col];
  }
  *(bf16x8*)(dstHi + (size_t)s * 512 + lane * 8) = hi;
}

__global__ void k_pack(const void* __restrict__ W1, const void* __restrict__ W2,
                       const void* __restrict__ W3, const void* __restrict__ Wmu,
                       const void* __restrict__ Wstd,
                       u16* pW1h, u16* pW1l, u16* pW2h, u16* pW2l,
                       u16* pW3h, u16* pW3l, u16* pHh, u16* pHl,
                       const void* __restrict__ v, float* __restrict__ xf,
                       u16* __restrict__ xh, u16* __restrict__ xl, int n4,
                       const int* __restrict__ flags,
                       int c1, int c2, int c3, int c4, int c5) {
  const int wflag = flags[1];   // vflag (weights share input dtype)
  const int b = blockIdx.x;
  const int tid = threadIdx.x;
  if (b < c1)      { wpack_dev(W1,   wflag, 384, 128, pW1h, pW1l, b,      tid); return; }
  if (b < c2)      { wpack_dev(W2,   wflag, 384, 256, pW2h, pW2l, b - c1, tid); return; }
  if (b < c3)      { wpack_dev(W3,   wflag, 768, 512, pW3h, pW3l, b - c2, tid); return; }
  if (b < c4)      { wpack_dev(Wmu,  wflag, 512, 256, pHh,           pHl,           b - c3, tid); return; }
  if (b < c5)      { wpack_dev(Wstd, wflag, 512, 256, pHh + 131072,  pHl + 131072,  b - c4, tid); return; }
  const int i = (b - c5) * 256 + tid;
  if (i >= n4) return;
  float val[4];
  if (wflag) {
    float4 t = ((const float4*)v)[i];
    val[0] = t.x; val[1] = t.y; val[2] = t.z; val[3] = t.w;
  } else {
    ushort4 t = ((const ushort4*)v)[i];
    val[0] = bf2f(t.x); val[1] = bf2f(t.y); val[2] = bf2f(t.z); val[3] = bf2f(t.w);
  }
  float4 fo; ushort4 ho, lo;
  u16 h;
  h = f2bf(val[0]); ho.x = h; lo.x = f2bf(val[0] - bf2f(h)); fo.x = val[0];
  h = f2bf(val[1]); ho.y = h; lo.y = f2bf(val[1] - bf2f(h)); fo.y = val[1];
  h = f2bf(val[2]); ho.z = h; lo.z = f2bf(val[2] - bf2f(h)); fo.z = val[2];
  h = f2bf(val[3]); ho.w = h; lo.w = f2bf(val[3] - bf2f(h)); fo.w = val[3];
  ((float4*)xf)[i] = fo;
  const int r  = i >> 5;
  const int k0 = (i & 31) << 2;
  const size_t pi = apidx(r, k0, 4);
  *(ushort4*)(xh + pi) = ho;
  *(ushort4*)(xl + pi) = lo;
}

// ---------------- preprocessing ----------------

__global__ void k_decode(const void* __restrict__ ei, const int* __restrict__ eflag,
                         int E, int N, int* __restrict__ rowi, int* __restrict__ coli,
                         float* __restrict__ deg, int* __restrict__ cnt) {
  int e = blockIdx.x * blockDim.x + threadIdx.x;
  if (e >= E) return;
  int f = *eflag;
  int r, c;
  if (f) {
    const long long* q = (const long long*)ei;
    r = (int)q[e]; c = (int)q[e + E];
  } else {
    const int* q = (const int*)ei;
    r = q[e]; c = q[e + E];
  }
  r = min(max(r, 0), N - 1);
  c = min(max(c, 0), N - 1);
  rowi[e] = r; coli[e] = c;
  atomicAdd(&deg[r], 1.0f);
  atomicAdd(&cnt[c], 1);
}

// 1024-thread shuffle scan fused with dis = rsqrt(deg)
__global__ __launch_bounds__(1024) void k_scan(const int* __restrict__ cnt,
                                               int* __restrict__ colPtr,
                                               int* __restrict__ cursor,
                                               const float* __restrict__ deg,
                                               float* __restrict__ dis, int n) {
  __shared__ int ws[16];
  const int t = threadIdx.x;
  const int lane = t & 63;
  const int w = t >> 6;
  int carry = 0;
  for (int base = 0; base < n; base += 1024) {
    int i = base + t;
    int v = (i < n) ? cnt[i] : 0;
    if (i < n) {
      float d = deg[i];
      dis[i] = (d > 0.f) ? rsqrtf(d) : 0.f;
    }
    int x = v;
#pragma unroll
    for (int off = 1; off < 64; off <<= 1) {
      int y = __shfl_up(x, off);
      if (lane >= off) x += y;
    }
    if (lane == 63) ws[w] = x;
    __syncthreads();
    if (w == 0) {
      int sv = (lane < 16) ? ws[lane] : 0;
#pragma unroll
      for (int off = 1; off < 16; off <<= 1) {
        int y = __shfl_up(sv, off);
        if (lane >= off) sv += y;
      }
      if (lane < 16) ws[lane] = sv;
    }
    __syncthreads();
    int woff = (w == 0) ? 0 : ws[w - 1];
    int incl = carry + woff + x;
    if (i < n) { colPtr[i + 1] = incl; cursor[i] = incl - v; }
    int tot = ws[15];
    __syncthreads();
    carry += tot;
  }
  if (t == 0) colPtr[0] = 0;
}

// place: CSC edge list as packed int2 {srcRow, w-bits}
__global__ void k_place(const int* __restrict__ rowi, const int* __restrict__ coli,
                        const float* __restrict__ dis, int* __restrict__ cursor,
                        int2* __restrict__ edges, int E) {
  int e = blockIdx.x * blockDim.x + threadIdx.x;
  if (e >= E) return;
  int r = rowi[e], c = coli[e];
  float wv = -dis[r] * dis[c];
  int pos = atomicAdd(&cursor[c], 1);
  edges[pos] = make_int2(r, __float_as_int(wv));
}

// ---------------- propagation F=128 (wave-per-node, 32 edges/round) ----------------
// Half-waves take even/odd edges; 16 pairs -> 16 independent float4 gathers in
// flight. Guarded metadata (w=0, r=0 beyond degree) lets rounds run full-width:
// NO serial tail (deg<=32 -> ONE latency round; Poisson(16) => 99.98% of nodes).
__global__ __launch_bounds__(256) void k_prop128(
    const float* __restrict__ z, const float* __restrict__ base,
    float* __restrict__ outF, u16* __restrict__ outH, u16* __restrict__ outL,
    const int* __restrict__ colPtr, const int2* __restrict__ edges,
    int N, float alpha, float beta) {
  const int lane = threadIdx.x & 63;
  const int c = blockIdx.x * 4 + (threadIdx.x >> 6);
  if (c >= N) return;
  const int half = lane >> 5;
  const int li = lane & 31;
  const int s = colPtr[c], e = colPtr[c + 1];
  float4 acc[4];
#pragma unroll
  for (int k = 0; k < 4; k++) acc[k] = make_float4(0.f, 0.f, 0.f, 0.f);

  for (int j0 = s; j0 < e; j0 += 64) {
    const int take = min(64, e - j0);
    int rI = 0; float wI = 0.f;
    if (j0 + lane < e) {
      int2 ew = edges[j0 + lane];
      rI = ew.x; wI = __int_as_float(ew.y);
    }
    for (int jj = 0; jj < take; jj += 32) {
      int rr[16]; float ww[16];
#pragma unroll
      for (int p = 0; p < 16; p++) {
        rr[p] = __shfl(rI, jj + 2 * p + half);
        ww[p] = __shfl(wI, jj + 2 * p + half);
      }
      float4 zz[16];
#pragma unroll
      for (int p = 0; p < 16; p++)
        zz[p] = *(const float4*)(z + (size_t)rr[p] * 128 + li * 4);
#pragma unroll
      for (int p = 0; p < 16; p++) {
        const float wk = ww[p];
        acc[p & 3].x = fmaf(wk, zz[p].x, acc[p & 3].x);
        acc[p & 3].y = fmaf(wk, zz[p].y, acc[p & 3].y);
        acc[p & 3].z = fmaf(wk, zz[p].z, acc[p & 3].z);
        acc[p & 3].w = fmaf(wk, zz[p].w, acc[p & 3].w);
      }
    }
  }

  float4 a;
  a.x = (acc[0].x + acc[1].x) + (acc[2].x + acc[3].x);
  a.y = (acc[0].y + acc[1].y) + (acc[2].y + acc[3].y);
  a.z = (acc[0].z + acc[1].z) + (acc[2].z + acc[3].z);
  a.w = (acc[0].w + acc[1].w) + (acc[2].w + acc[3].w);
  a.x += __shfl_xor(a.x, 32);
  a.y += __shfl_xor(a.y, 32);
  a.z += __shfl_xor(a.z, 32);
  a.w += __shfl_xor(a.w, 32);

  if (lane < 32) {
    float vv[4] = {alpha * a.x, alpha * a.y, alpha * a.z, alpha * a.w};
    const size_t o = (size_t)c * 128 + li * 4;
    if (base != nullptr) {
      float4 b = *(const float4*)(base + o);
      vv[0] = fmaf(beta, b.x, vv[0]); vv[1] = fmaf(beta, b.y, vv[1]);
      vv[2] = fmaf(beta, b.z, vv[2]); vv[3] = fmaf(beta, b.w, vv[3]);
    }
    if (outF) *(float4*)(outF + o) = make_float4(vv[0], vv[1], vv[2], vv[3]);
    ushort4 ho, lo;
    u16 h;
    h = f2bf(vv[0]); ho.x = h; lo.x = f2bf(vv[0] - bf2f(h));
    h = f2bf(vv[1]); ho.y = h; lo.y = f2bf(vv[1] - bf2f(h));
    h = f2bf(vv[2]); ho.z = h; lo.z = f2bf(vv[2] - bf2f(h));
    h = f2bf(vv[3]); ho.w = h; lo.w = f2bf(vv[3] - bf2f(h));
    const size_t pi = apidx(c, li << 2, 4);    // A-pack, Fi=128
    *(ushort4*)(outH + pi) = ho;
    *(ushort4*)(outL + pi) = lo;
  }
}

// ---------------- propagation F=256 (wave-per-node, 16 gathers/round) ----------------
__global__ __launch_bounds__(256) void k_prop256(
    const float* __restrict__ z, const float* __restrict__ base,
    float* __restrict__ outF, u16* __restrict__ outH, u16* __restrict__ outL,
    const int* __restrict__ colPtr, const int2* __restrict__ edges,
    int N, float alpha, float beta) {
  const int lane = threadIdx.x & 63;
  const int c = blockIdx.x * 4 + (threadIdx.x >> 6);
  if (c >= N) return;
  const int s = colPtr[c], e = colPtr[c + 1];
  float4 acc[4];
#pragma unroll
  for (int k = 0; k < 4; k++) acc[k] = make_float4(0.f, 0.f, 0.f, 0.f);

  for (int j0 = s; j0 < e; j0 += 64) {
    const int take = min(64, e - j0);
    int rI = 0; float wI = 0.f;
    if (j0 + lane < e) {
      int2 ew = edges[j0 + lane];
      rI = ew.x; wI = __int_as_float(ew.y);
    }
    for (int jj = 0; jj < take; jj += 16) {
      int rr[16]; float ww[16];
#pragma unroll
      for (int k = 0; k < 16; k++) {
        rr[k] = __shfl(rI, jj + k);
        ww[k] = __shfl(wI, jj + k);
      }
      float4 zz[16];
#pragma unroll
      for (int k = 0; k < 16; k++)
        zz[k] = *(const float4*)(z + (size_t)rr[k] * 256 + lane * 4);
#pragma unroll
      for (int k = 0; k < 16; k++) {
        const float wk = ww[k];
        acc[k & 3].x = fmaf(wk, zz[k].x, acc[k & 3].x);
        acc[k & 3].y = fmaf(wk, zz[k].y, acc[k & 3].y);
        acc[k & 3].z = fmaf(wk, zz[k].z, acc[k & 3].z);
        acc[k & 3].w = fmaf(wk, zz[k].w, acc[k & 3].w);
      }
    }
  }

  float vv[4] = {alpha * ((acc[0].x + acc[1].x) + (acc[2].x + acc[3].x)),
                 alpha * ((acc[0].y + acc[1].y) + (acc[2].y + acc[3].y)),
                 alpha * ((acc[0].z + acc[1].z) + (acc[2].z + acc[3].z)),
                 alpha * ((acc[0].w + acc[1].w) + (acc[2].w + acc[3].w))};
  const size_t o = (size_t)c * 256 + lane * 4;
  if (base != nullptr) {
    float4 b = *(const float4*)(base + o);
    vv[0] = fmaf(beta, b.x, vv[0]); vv[1] = fmaf(beta, b.y, vv[1]);
    vv[2] = fmaf(beta, b.z, vv[2]); vv[3] = fmaf(beta, b.w, vv[3]);
  }
  if (outF) *(float4*)(outF + o) = make_float4(vv[0], vv[1], vv[2], vv[3]);
  ushort4 ho, lo;
  u16 h;
  h = f2bf(vv[0]); ho.x = h; lo.x = f2bf(vv[0] - bf2f(h));
  h = f2bf(vv[1]); ho.y = h; lo.y = f2bf(vv[1] - bf2f(h));
  h = f2bf(vv[2]); ho.z = h; lo.z = f2bf(vv[2] - bf2f(h));
  h = f2bf(vv[3]); ho.w = h; lo.w = f2bf(vv[3] - bf2f(h));
  const size_t pi = apidx(c, lane << 2, 8);    // A-pack, Fi=256
  *(ushort4*)(outH + pi) = ho;
  *(ushort4*)(outL + pi) = lo;
}

// ---------------- MFMA GEMM (LDS-FREE, barrier-free, XCD swizzle; FROZEN) ----------------
// r8-measured floor for this problem size (46.3us L3 ~ 341 TF ~ m97-ladder).
// Both operands pre-packed fragment-linear in global; fragments load direct
// to VGPR as coalesced 16B/lane; no LDS, no barriers.
// C/D mapping (verified): col = lane&31, row = (reg&3)+8*(reg>>2)+4*(lane>>5).
__global__ __launch_bounds__(256, 4) void k_gemm_mfma(
    const u16* __restrict__ a0h, const u16* __restrict__ a0l,
    const u16* __restrict__ a1h, const u16* __restrict__ a1l,
    const u16* __restrict__ a2h, const u16* __restrict__ a2l,
    const u16* __restrict__ packHi, const u16* __restrict__ packLo,
    const void* __restrict__ bias, const void* __restrict__ bias2,
    const int* __restrict__ wflagp,
    int N, int Fi, int NQ, int Fo,
    float* __restrict__ outF, u16* __restrict__ outH, u16* __restrict__ outL,
    u16* __restrict__ outB16, float* __restrict__ outB32, int relu, int headSplit) {
  const int wflag = *wflagp;
  const int tid  = threadIdx.x;
  const int lane = tid & 63;
  const int w    = tid >> 6;
  const int wm   = w >> 1;
  const int wn   = w & 1;

  const int gx = gridDim.x;
  int wg = blockIdx.x + gx * blockIdx.y;
  {
    const int nwg = gx * gridDim.y;
    const int q = nwg >> 3, r = nwg & 7;
    const int xcd = wg & 7;
    const int idx = wg >> 3;
    wg = (xcd < r ? xcd * (q + 1) : r * (q + 1) + (xcd - r) * q) + idx;
  }
  const int nt = wg % gx;
  const int mt = wg / gx;
  const int n0 = nt << 6;
  const int m0 = mt << 6;
  const int KSQ   = Fi >> 5;
  const int qsh   = __builtin_ctz(KSQ);
  const int qmask = KSQ - 1;
  const int KS    = NQ << qsh;

  const int laneoff = lane << 3;

  f32x16 acc = {};

#pragma unroll 2
  for (int ks = 0; ks < KS; ks++) {
    const int q   = ks >> qsh;
    const int ksl = ks & qmask;
    const u16* Ah = (q == 0) ? a0h : (q == 1 ? a1h : a2h);
    const u16* Al = (q == 0) ? a0l : (q == 1 ? a1l : a2l);
    const size_t abase = ((size_t)(mt * KSQ + ksl) << 2) * 512 + (size_t)((wm << 1) * 512) + laneoff;
    const bf16x8 aH0 = *(const bf16x8*)(Ah + abase);
    const bf16x8 aH1 = *(const bf16x8*)(Ah + abase + 512);
    const bf16x8 aL0 = *(const bf16x8*)(Al + abase);
    const bf16x8 aL1 = *(const bf16x8*)(Al + abase + 512);
    const size_t bbase = (((size_t)(nt * KS + ks) << 2) + (wn << 1)) * 512 + laneoff;
    const bf16x8 b0 = *(const bf16x8*)(packHi + bbase);
    const bf16x8 b1 = *(const bf16x8*)(packHi + bbase + 512);

    acc = __builtin_amdgcn_mfma_f32_32x32x16_bf16(aH0, b0, acc, 0, 0, 0);
    acc = __builtin_amdgcn_mfma_f32_32x32x16_bf16(aL0, b0, acc, 0, 0, 0);
    acc = __builtin_amdgcn_mfma_f32_32x32x16_bf16(aH1, b1, acc, 0, 0, 0);
    acc = __builtin_amdgcn_mfma_f32_32x32x16_bf16(aL1, b1, acc, 0, 0, 0);
    if (wflag) {
      const bf16x8 c0 = *(const bf16x8*)(packLo + bbase);
      const bf16x8 c1 = *(const bf16x8*)(packLo + bbase + 512);
      acc = __builtin_amdgcn_mfma_f32_32x32x16_bf16(aH0, c0, acc, 0, 0, 0);
      acc = __builtin_amdgcn_mfma_f32_32x32x16_bf16(aH1, c1, acc, 0, 0, 0);
    }
  }

  {
    const int ncol = n0 + (wn << 5) + (lane & 31);
    const int KSQo = Fo >> 5;
    int col = ncol;
    const void* bp = bias;
    size_t obase = 0;
    int FoOut = Fo;
    if (headSplit) {
      FoOut = 256;
      if (ncol >= 256) { col = ncol - 256; bp = bias2; obase = (size_t)N * 256; }
    }
    const float bv = wflag ? ((const float*)bp)[col]
                           : bf2f(((const u16*)bp)[col]);
#pragma unroll
    for (int r = 0; r < 16; r++) {
      const int m = m0 + (wm << 5) + (r & 3) + ((r >> 2) << 3) + ((lane >> 5) << 2);
      if (m < N) {
        float vv = acc[r] + bv;
        if (relu) vv = fmaxf(vv, 0.f);
        if (outF) outF[(size_t)m * Fo + ncol] = vv;
        if (outH) {
          u16 h = f2bf(vv);
          const size_t pi = apidx(m, ncol, KSQo);
          outH[pi] = h;
          outL[pi] = f2bf(vv - bf2f(h));
        }
        if (outB16) {
          const size_t o = obase + (size_t)m * FoOut + col;
          if (wflag) outB32[o] = vv;
          else       outB16[o] = f2bf(vv);
        }
      }
    }
  }
}

// ---------------- host (kernel launches ONLY) ----------------

static size_t align256(size_t x) { return (x + 255) & ~(size_t)255; }

extern "C" void kernel_launch(void* const* d_in, const int* in_sizes, int n_in,
                              void* d_out, int out_size, void* d_ws, size_t ws_size,
                              hipStream_t stream) {
  const void* v    = d_in[0];
  const void* ei   = d_in[1];
  const void* W1   = d_in[2];
  const void* b1   = d_in[3];
  const void* W2   = d_in[4];
  const void* b2   = d_in[5];
  const void* W3   = d_in[6];
  const void* b3   = d_in[7];
  const void* Wmu  = d_in[8];
  const void* bmu  = d_in[9];
  const void* Wstd = d_in[10];
  const void* bstd = d_in[11];
  (void)n_in; (void)ws_size;

  const int N = in_sizes[0] / 128;   // 10000
  const int E = in_sizes[1] / 2;     // 160000
  const size_t NP = ((size_t)N + 63) & ~(size_t)63;

  char* base = (char*)d_ws;
  size_t off = 0;
  auto carve = [&](size_t bytes) { void* p = base + off; off = align256(off + bytes); return p; };

  int*   eflag  = (int*)  carve(4);      // flags[0]=eflag, flags[1]=vflag
  int*   vflag  = (int*)  carve(4);
  int*   rowi   = (int*)  carve((size_t)E * 4);
  int*   coli   = (int*)  carve((size_t)E * 4);
  float* deg    = (float*)carve((size_t)N * 4);
  float* dis    = (float*)carve((size_t)N * 4);
  int*   cnt    = (int*)  carve((size_t)N * 4);
  int*   colPtr = (int*)  carve((size_t)(N + 1) * 4);
  int*   cursor = (int*)  carve((size_t)N * 4);
  int2*  edges  = (int2*) carve((size_t)E * 8);

  u16* pW1h = (u16*)carve((size_t)384 * 128 * 2);
  u16* pW1l = (u16*)carve((size_t)384 * 128 * 2);
  u16* pW2h = (u16*)carve((size_t)384 * 256 * 2);
  u16* pW2l = (u16*)carve((size_t)384 * 256 * 2);
  u16* pW3h = (u16*)carve((size_t)768 * 512 * 2);
  u16* pW3l = (u16*)carve((size_t)768 * 512 * 2);
  u16* pHh  = (u16*)carve((size_t)2 * 512 * 256 * 2);
  u16* pHl  = (u16*)carve((size_t)2 * 512 * 256 * 2);

  float* Xf  = (float*)carve(NP * 256 * 4);
  u16*   Xh  = (u16*)  carve(NP * 256 * 2);
  u16*   Xl  = (u16*)  carve(NP * 256 * 2);
  float* Yf  = (float*)carve(NP * 128 * 4);
  u16*   Yh  = (u16*)  carve(NP * 512 * 2);
  u16*   Yl  = (u16*)  carve(NP * 512 * 2);
  float* t1f = (float*)carve(NP * 256 * 4);
  u16*   t1h = (u16*)  carve(NP * 256 * 2);
  u16*   t1l = (u16*)  carve(NP * 256 * 2);
  u16*   t2h = (u16*)  carve(NP * 256 * 2);
  u16*   t2l = (u16*)  carve(NP * 256 * 2);

  // 1) fused probes + zero + sentinel
  const int zb = (N + 255) / 256;
  const int sb = (out_size + 255) / 256;
  k_init<<<2 + zb + sb, 256, 0, stream>>>((const unsigned*)v, 1024, vflag,
                                          (const unsigned*)ei, 2048, eflag,
                                          deg, cnt, N, zb, (u16*)d_out, out_size);

  // 2) fused weight packs + input convert
  const int n4 = N * 128 / 4;
  const int c1 = 24, c2 = c1 + 48, c3 = c2 + 192, c4 = c3 + 64, c5 = c4 + 64;
  const int cTot = c5 + (n4 + 255) / 256;
  k_pack<<<cTot, 256, 0, stream>>>(W1, W2, W3, Wmu, Wstd,
                                   pW1h, pW1l, pW2h, pW2l, pW3h, pW3l, pHh, pHl,
                                   v, Xf, Xh, Xl, n4, eflag,
                                   c1, c2, c3, c4, c5);

  // 3) graph preprocessing (decode -> scan+dis -> place)
  k_decode<<<(E + 255) / 256, 256, 0, stream>>>(ei, eflag, E, N, rowi, coli, deg, cnt);
  k_scan<<<1, 1024, 0, stream>>>(cnt, colPtr, cursor, deg, dis, N);
  k_place<<<(E + 255) / 256, 256, 0, stream>>>(rowi, coli, dis, cursor, edges, E);

  const int gM = (N + 63) / 64;
  const int gP = (N + 3) / 4;

  // layer 1: Fi=128 -> Fo=128, X -> Y
  k_prop128<<<gP, 256, 0, stream>>>(Xf, nullptr, t1f, t1h, t1l, colPtr, edges, N, 1.f, 0.f);
  k_prop128<<<gP, 256, 0, stream>>>(t1f, Xf, nullptr, t2h, t2l, colPtr, edges, N, 2.f, -1.f);
  k_gemm_mfma<<<dim3(2, gM), 256, 0, stream>>>(Xh, Xl, t1h, t1l, t2h, t2l, pW1h, pW1l,
                                               b1, b1, vflag, N, 128, 3, 128,
                                               Yf, Yh, Yl, nullptr, nullptr, 1, 0);

  // layer 2: Fi=128 -> Fo=256, Y -> X
  k_prop128<<<gP, 256, 0, stream>>>(Yf, nullptr, t1f, t1h, t1l, colPtr, edges, N, 1.f, 0.f);
  k_prop128<<<gP, 256, 0, stream>>>(t1f, Yf, nullptr, t2h, t2l, colPtr, edges, N, 2.f, -1.f);
  k_gemm_mfma<<<dim3(4, gM), 256, 0, stream>>>(Yh, Yl, t1h, t1l, t2h, t2l, pW2h, pW2l,
                                               b2, b2, vflag, N, 128, 3, 256,
                                               Xf, Xh, Xl, nullptr, nullptr, 1, 0);

  // layer 3: Fi=256 -> Fo=512, X -> Y (packs only)
  k_prop256<<<gP, 256, 0, stream>>>(Xf, nullptr, t1f, t1h, t1l, colPtr, edges, N, 1.f, 0.f);
  k_prop256<<<gP, 256, 0, stream>>>(t1f, Xf, nullptr, t2h, t2l, colPtr, edges, N, 2.f, -1.f);
  k_gemm_mfma<<<dim3(8, gM), 256, 0, stream>>>(Xh, Xl, t1h, t1l, t2h, t2l, pW3h, pW3l,
                                               b3, b3, vflag, N, 256, 3, 512,
                                               nullptr, Yh, Yl, nullptr, nullptr, 1, 0);

  // fused heads
  k_gemm_mfma<<<dim3(8, gM), 256, 0, stream>>>(Yh, Yl, nullptr, nullptr, nullptr, nullptr,
                                               pHh, pHl, bmu, bstd, vflag, N, 512, 1, 512,
                                               nullptr, nullptr, nullptr,
                                               (u16*)d_out, (float*)d_out, 0, 1);
}

// Round 11
// 314.193 us; speedup vs baseline: 1.1015x; 1.1015x over previous
//
#include <hip/hip_runtime.h>
#include <hip/hip_bf16.h>

// ---------------- types & helpers ----------------

typedef __attribute__((ext_vector_type(8)))  short bf16x8;   // 8 bf16 = 4 VGPR
typedef __attribute__((ext_vector_type(16))) float f32x16;   // MFMA 32x32 acc
typedef unsigned short u16;

__device__ __forceinline__ u16 f2bf(float x) {               // RNE fp32->bf16
  union { float f; unsigned u; } c; c.f = x;
  return (u16)((c.u + 0x7fffu + ((c.u >> 16) & 1u)) >> 16);
}
__device__ __forceinline__ float bf2f(u16 u) {               // exact bf16->fp32
  union { unsigned u; float f; } c; c.u = ((unsigned)u) << 16;
  return c.f;
}

// A-pack addressing (fragment-linear, 64-row m-tiles, 32-k ksteps).
// Element (row r, col k), KSQ = Fi/32:
//   slot = ((r>>6)*KSQ + (k>>5))*4 + ((r>>5)&1)*2 + ((k>>4)&1)
//   lane = (r&31) + ((k>>3)&1)*32 ;  j = k&7 ;  idx = slot*512 + lane*8 + j
__device__ __forceinline__ size_t apidx(int r, int k, int KSQ) {
  const int slot = (((r >> 6) * KSQ + (k >> 5)) << 2) + (((r >> 5) & 1) << 1) + ((k >> 4) & 1);
  return ((size_t)slot << 9) + (size_t)(((((k >> 3) & 1) << 5) | (r & 31)) << 3) + (k & 7);
}

// ---------------- fused init: dtype probes + zero + sentinel ----------------
__global__ void k_init(const unsigned* __restrict__ v, int nv, int* __restrict__ vflag,
                       const unsigned* __restrict__ ei, int ne, int* __restrict__ eflag,
                       float* __restrict__ deg, int* __restrict__ cnt, int n, int zb,
                       u16* __restrict__ outSent, int outN) {
  __shared__ unsigned red[256];
  if (blockIdx.x == 0) {
    int ok = 0;
    for (int i = threadIdx.x; i < nv; i += 256) {
      unsigned lo = v[i] & 0xffffu;
      unsigned ef = (lo >> 7) & 0xffu;
      if (ef >= 115u && ef <= 140u) ok++;
    }
    red[threadIdx.x] = (unsigned)ok;
    __syncthreads();
    for (int s = 128; s > 0; s >>= 1) {
      if (threadIdx.x < s) red[threadIdx.x] += red[threadIdx.x + s];
      __syncthreads();
    }
    if (threadIdx.x == 0) *vflag = ((int)red[0] < nv / 2) ? 1 : 0;
  } else if (blockIdx.x == 1) {
    unsigned acc = 0;
    for (int i = threadIdx.x; i < ne; i += 256)
      if (i & 1) acc |= ei[i];
    red[threadIdx.x] = acc;
    __syncthreads();
    for (int s = 128; s > 0; s >>= 1) {
      if (threadIdx.x < s) red[threadIdx.x] |= red[threadIdx.x + s];
      __syncthreads();
    }
    if (threadIdx.x == 0) *eflag = (red[0] == 0u) ? 1 : 0;
  } else if (blockIdx.x < 2 + zb) {
    int i = (blockIdx.x - 2) * 256 + threadIdx.x;
    if (i < n) { deg[i] = 0.0f; cnt[i] = 0; }
  } else {
    int i = (blockIdx.x - 2 - zb) * 256 + threadIdx.x;
    if (i < outN) outSent[i] = 0x3F00;
  }
}

// ---------------- fused pack: 5 weight packs + input convert ----------------
__device__ __forceinline__ void wpack_dev(
    const void* __restrict__ W, int wflag, int K, int Fo,
    u16* __restrict__ dstHi, u16* __restrict__ dstLo, int blk, int tid) {
  const int t = blk * 256 + tid;
  const int KS = K >> 5;
  const int total = (Fo >> 6) * KS * 4;
  const int s = t >> 6;
  if (s >= total) return;
  const int lane = t & 63;
  const int fb = s & 3;
  const int sk = s >> 2;
  const int ks = sk % KS;
  const int nt = sk / KS;
  const int col = (nt << 6) + ((fb >> 1) << 5) + (lane & 31);
  const int row = (ks << 5) + ((fb & 1) << 4) + ((lane >> 5) << 3);
  bf16x8 hi;
  if (wflag) {
    const float* Wf = (const float*)W;
    bf16x8 lo;
#pragma unroll
    for (int j = 0; j < 8; j++) {
      float wv = Wf[(size_t)(row + j) * Fo + col];
      u16 h = f2bf(wv);
      hi[j] = (short)h;
      lo[j] = (short)f2bf(wv - bf2f(h));
    }
    *(bf16x8*)(dstLo + (size_t)s * 512 + lane * 8) = lo;
  } else {
    const u16* Wb = (const u16*)W;
#pragma unroll
    for (int j = 0; j < 8; j++)
      hi[j] = (short)Wb[(size_t)(row + j) * Fo + col];
  }
  *(bf16x8*)(dstHi + (size_t)s * 512 + lane * 8) = hi;
}

__global__ void k_pack(const void* __restrict__ W1, const void* __restrict__ W2,
                       const void* __restrict__ W3, const void* __restrict__ Wmu,
                       const void* __restrict__ Wstd,
                       u16* pW1h, u16* pW1l, u16* pW2h, u16* pW2l,
                       u16* pW3h, u16* pW3l, u16* pHh, u16* pHl,
                       const void* __restrict__ v, u16* __restrict__ xb,
                       u16* __restrict__ xh, u16* __restrict__ xl, int n4,
                       const int* __restrict__ flags,
                       int c1, int c2, int c3, int c4, int c5) {
  const int wflag = flags[1];   // vflag (weights share input dtype)
  const int b = blockIdx.x;
  const int tid = threadIdx.x;
  if (b < c1)      { wpack_dev(W1,   wflag, 384, 128, pW1h, pW1l, b,      tid); return; }
  if (b < c2)      { wpack_dev(W2,   wflag, 384, 256, pW2h, pW2l, b - c1, tid); return; }
  if (b < c3)      { wpack_dev(W3,   wflag, 768, 512, pW3h, pW3l, b - c2, tid); return; }
  if (b < c4)      { wpack_dev(Wmu,  wflag, 512, 256, pHh,           pHl,           b - c3, tid); return; }
  if (b < c5)      { wpack_dev(Wstd, wflag, 512, 256, pHh + 131072,  pHl + 131072,  b - c4, tid); return; }
  const int i = (b - c5) * 256 + tid;
  if (i >= n4) return;
  float val[4];
  if (wflag) {
    float4 t = ((const float4*)v)[i];
    val[0] = t.x; val[1] = t.y; val[2] = t.z; val[3] = t.w;
  } else {
    ushort4 t = ((const ushort4*)v)[i];
    val[0] = bf2f(t.x); val[1] = bf2f(t.y); val[2] = bf2f(t.z); val[3] = bf2f(t.w);
  }
  ushort4 ho, lo;
  u16 h;
  h = f2bf(val[0]); ho.x = h; lo.x = f2bf(val[0] - bf2f(h));
  h = f2bf(val[1]); ho.y = h; lo.y = f2bf(val[1] - bf2f(h));
  h = f2bf(val[2]); ho.z = h; lo.z = f2bf(val[2] - bf2f(h));
  h = f2bf(val[3]); ho.w = h; lo.w = f2bf(val[3] - bf2f(h));
  *(ushort4*)(xb + (size_t)i * 4) = ho;      // bf16 row-major plane (prop input)
  const int r  = i >> 5;
  const int k0 = (i & 31) << 2;
  const size_t pi = apidx(r, k0, 4);
  *(ushort4*)(xh + pi) = ho;
  *(ushort4*)(xl + pi) = lo;
}

// ---------------- preprocessing ----------------

__global__ void k_decode(const void* __restrict__ ei, const int* __restrict__ eflag,
                         int E, int N, int* __restrict__ rowi, int* __restrict__ coli,
                         float* __restrict__ deg, int* __restrict__ cnt) {
  int e = blockIdx.x * blockDim.x + threadIdx.x;
  if (e >= E) return;
  int f = *eflag;
  int r, c;
  if (f) {
    const long long* q = (const long long*)ei;
    r = (int)q[e]; c = (int)q[e + E];
  } else {
    const int* q = (const int*)ei;
    r = q[e]; c = q[e + E];
  }
  r = min(max(r, 0), N - 1);
  c = min(max(c, 0), N - 1);
  rowi[e] = r; coli[e] = c;
  atomicAdd(&deg[r], 1.0f);
  atomicAdd(&cnt[c], 1);
}

// 1024-thread shuffle scan fused with dis = rsqrt(deg)
__global__ __launch_bounds__(1024) void k_scan(const int* __restrict__ cnt,
                                               int* __restrict__ colPtr,
                                               int* __restrict__ cursor,
                                               const float* __restrict__ deg,
                                               float* __restrict__ dis, int n) {
  __shared__ int ws[16];
  const int t = threadIdx.x;
  const int lane = t & 63;
  const int w = t >> 6;
  int carry = 0;
  for (int base = 0; base < n; base += 1024) {
    int i = base + t;
    int v = (i < n) ? cnt[i] : 0;
    if (i < n) {
      float d = deg[i];
      dis[i] = (d > 0.f) ? rsqrtf(d) : 0.f;
    }
    int x = v;
#pragma unroll
    for (int off = 1; off < 64; off <<= 1) {
      int y = __shfl_up(x, off);
      if (lane >= off) x += y;
    }
    if (lane == 63) ws[w] = x;
    __syncthreads();
    if (w == 0) {
      int sv = (lane < 16) ? ws[lane] : 0;
#pragma unroll
      for (int off = 1; off < 16; off <<= 1) {
        int y = __shfl_up(sv, off);
        if (lane >= off) sv += y;
      }
      if (lane < 16) ws[lane] = sv;
    }
    __syncthreads();
    int woff = (w == 0) ? 0 : ws[w - 1];
    int incl = carry + woff + x;
    if (i < n) { colPtr[i + 1] = incl; cursor[i] = incl - v; }
    int tot = ws[15];
    __syncthreads();
    carry += tot;
  }
  if (t == 0) colPtr[0] = 0;
}

// place: CSC edge list as packed int2 {srcRow, w-bits}
__global__ void k_place(const int* __restrict__ rowi, const int* __restrict__ coli,
                        const float* __restrict__ dis, int* __restrict__ cursor,
                        int2* __restrict__ edges, int E) {
  int e = blockIdx.x * blockDim.x + threadIdx.x;
  if (e >= E) return;
  int r = rowi[e], c = coli[e];
  float wv = -dis[r] * dis[c];
  int pos = atomicAdd(&cursor[c], 1);
  edges[pos] = make_int2(r, __float_as_int(wv));
}

// ---------------- propagation F=128 (bf16 gather, wave-per-node) ----------------
// Gathers BF16 rows (256B vs fp32's 512B -> HALF the traffic; props are
// traffic-bound per r10's MLP-null). Convert in-register, accumulate fp32.
// Half-waves take even/odd edges; 16 pairs/round; guarded full-width rounds.
__global__ __launch_bounds__(256) void k_prop128(
    const u16* __restrict__ z, const u16* __restrict__ base,
    u16* __restrict__ outB, u16* __restrict__ outH, u16* __restrict__ outL,
    const int* __restrict__ colPtr, const int2* __restrict__ edges,
    int N, float alpha, float beta) {
  const int lane = threadIdx.x & 63;
  const int c = blockIdx.x * 4 + (threadIdx.x >> 6);
  if (c >= N) return;
  const int half = lane >> 5;
  const int li = lane & 31;
  const int s = colPtr[c], e = colPtr[c + 1];
  float4 acc[4];
#pragma unroll
  for (int k = 0; k < 4; k++) acc[k] = make_float4(0.f, 0.f, 0.f, 0.f);

  for (int j0 = s; j0 < e; j0 += 64) {
    const int take = min(64, e - j0);
    int rI = 0; float wI = 0.f;
    if (j0 + lane < e) {
      int2 ew = edges[j0 + lane];
      rI = ew.x; wI = __int_as_float(ew.y);
    }
    for (int jj = 0; jj < take; jj += 32) {
      int rr[16]; float ww[16];
#pragma unroll
      for (int p = 0; p < 16; p++) {
        rr[p] = __shfl(rI, jj + 2 * p + half);
        ww[p] = __shfl(wI, jj + 2 * p + half);
      }
      ushort4 zz[16];
#pragma unroll
      for (int p = 0; p < 16; p++)
        zz[p] = *(const ushort4*)(z + (size_t)rr[p] * 128 + li * 4);
#pragma unroll
      for (int p = 0; p < 16; p++) {
        const float wk = ww[p];
        acc[p & 3].x = fmaf(wk, bf2f(zz[p].x), acc[p & 3].x);
        acc[p & 3].y = fmaf(wk, bf2f(zz[p].y), acc[p & 3].y);
        acc[p & 3].z = fmaf(wk, bf2f(zz[p].z), acc[p & 3].z);
        acc[p & 3].w = fmaf(wk, bf2f(zz[p].w), acc[p & 3].w);
      }
    }
  }

  float4 a;
  a.x = (acc[0].x + acc[1].x) + (acc[2].x + acc[3].x);
  a.y = (acc[0].y + acc[1].y) + (acc[2].y + acc[3].y);
  a.z = (acc[0].z + acc[1].z) + (acc[2].z + acc[3].z);
  a.w = (acc[0].w + acc[1].w) + (acc[2].w + acc[3].w);
  a.x += __shfl_xor(a.x, 32);
  a.y += __shfl_xor(a.y, 32);
  a.z += __shfl_xor(a.z, 32);
  a.w += __shfl_xor(a.w, 32);

  if (lane < 32) {
    float vv[4] = {alpha * a.x, alpha * a.y, alpha * a.z, alpha * a.w};
    const size_t o = (size_t)c * 128 + li * 4;
    if (base != nullptr) {
      ushort4 b = *(const ushort4*)(base + o);
      vv[0] = fmaf(beta, bf2f(b.x), vv[0]); vv[1] = fmaf(beta, bf2f(b.y), vv[1]);
      vv[2] = fmaf(beta, bf2f(b.z), vv[2]); vv[3] = fmaf(beta, bf2f(b.w), vv[3]);
    }
    ushort4 ho, lo;
    u16 h;
    h = f2bf(vv[0]); ho.x = h; lo.x = f2bf(vv[0] - bf2f(h));
    h = f2bf(vv[1]); ho.y = h; lo.y = f2bf(vv[1] - bf2f(h));
    h = f2bf(vv[2]); ho.z = h; lo.z = f2bf(vv[2] - bf2f(h));
    h = f2bf(vv[3]); ho.w = h; lo.w = f2bf(vv[3] - bf2f(h));
    if (outB) *(ushort4*)(outB + o) = ho;     // bf16 row-major (next prop)
    const size_t pi = apidx(c, li << 2, 4);   // A-pack, Fi=128 (GEMM)
    *(ushort4*)(outH + pi) = ho;
    *(ushort4*)(outL + pi) = lo;
  }
}

// ---------------- propagation F=256 (bf16 gather, wave-per-node) ----------------
__global__ __launch_bounds__(256) void k_prop256(
    const u16* __restrict__ z, const u16* __restrict__ base,
    u16* __restrict__ outB, u16* __restrict__ outH, u16* __restrict__ outL,
    const int* __restrict__ colPtr, const int2* __restrict__ edges,
    int N, float alpha, float beta) {
  const int lane = threadIdx.x & 63;
  const int c = blockIdx.x * 4 + (threadIdx.x >> 6);
  if (c >= N) return;
  const int s = colPtr[c], e = colPtr[c + 1];
  float4 acc[4];
#pragma unroll
  for (int k = 0; k < 4; k++) acc[k] = make_float4(0.f, 0.f, 0.f, 0.f);

  for (int j0 = s; j0 < e; j0 += 64) {
    const int take = min(64, e - j0);
    int rI = 0; float wI = 0.f;
    if (j0 + lane < e) {
      int2 ew = edges[j0 + lane];
      rI = ew.x; wI = __int_as_float(ew.y);
    }
    for (int jj = 0; jj < take; jj += 16) {
      int rr[16]; float ww[16];
#pragma unroll
      for (int k = 0; k < 16; k++) {
        rr[k] = __shfl(rI, jj + k);
        ww[k] = __shfl(wI, jj + k);
      }
      ushort4 zz[16];
#pragma unroll
      for (int k = 0; k < 16; k++)
        zz[k] = *(const ushort4*)(z + (size_t)rr[k] * 256 + lane * 4);
#pragma unroll
      for (int k = 0; k < 16; k++) {
        const float wk = ww[k];
        acc[k & 3].x = fmaf(wk, bf2f(zz[k].x), acc[k & 3].x);
        acc[k & 3].y = fmaf(wk, bf2f(zz[k].y), acc[k & 3].y);
        acc[k & 3].z = fmaf(wk, bf2f(zz[k].z), acc[k & 3].z);
        acc[k & 3].w = fmaf(wk, bf2f(zz[k].w), acc[k & 3].w);
      }
    }
  }

  float vv[4] = {alpha * ((acc[0].x + acc[1].x) + (acc[2].x + acc[3].x)),
                 alpha * ((acc[0].y + acc[1].y) + (acc[2].y + acc[3].y)),
                 alpha * ((acc[0].z + acc[1].z) + (acc[2].z + acc[3].z)),
                 alpha * ((acc[0].w + acc[1].w) + (acc[2].w + acc[3].w))};
  const size_t o = (size_t)c * 256 + lane * 4;
  if (base != nullptr) {
    ushort4 b = *(const ushort4*)(base + o);
    vv[0] = fmaf(beta, bf2f(b.x), vv[0]); vv[1] = fmaf(beta, bf2f(b.y), vv[1]);
    vv[2] = fmaf(beta, bf2f(b.z), vv[2]); vv[3] = fmaf(beta, bf2f(b.w), vv[3]);
  }
  ushort4 ho, lo;
  u16 h;
  h = f2bf(vv[0]); ho.x = h; lo.x = f2bf(vv[0] - bf2f(h));
  h = f2bf(vv[1]); ho.y = h; lo.y = f2bf(vv[1] - bf2f(h));
  h = f2bf(vv[2]); ho.z = h; lo.z = f2bf(vv[2] - bf2f(h));
  h = f2bf(vv[3]); ho.w = h; lo.w = f2bf(vv[3] - bf2f(h));
  if (outB) *(ushort4*)(outB + o) = ho;
  const size_t pi = apidx(c, lane << 2, 8);    // A-pack, Fi=256
  *(ushort4*)(outH + pi) = ho;
  *(ushort4*)(outL + pi) = lo;
}

// ---------------- MFMA GEMM (LDS-FREE, barrier-free, XCD swizzle; FROZEN) ----------------
// r8-measured floor for this problem size. Both operands pre-packed
// fragment-linear in global; fragments load direct to VGPR; no LDS/barriers.
// outB: bf16 row-major plane for the next layer's props (replaces fp32 outF).
// C/D mapping (verified): col = lane&31, row = (reg&3)+8*(reg>>2)+4*(lane>>5).
__global__ __launch_bounds__(256, 4) void k_gemm_mfma(
    const u16* __restrict__ a0h, const u16* __restrict__ a0l,
    const u16* __restrict__ a1h, const u16* __restrict__ a1l,
    const u16* __restrict__ a2h, const u16* __restrict__ a2l,
    const u16* __restrict__ packHi, const u16* __restrict__ packLo,
    const void* __restrict__ bias, const void* __restrict__ bias2,
    const int* __restrict__ wflagp,
    int N, int Fi, int NQ, int Fo,
    u16* __restrict__ outB, u16* __restrict__ outH, u16* __restrict__ outL,
    u16* __restrict__ outB16, float* __restrict__ outB32, int relu, int headSplit) {
  const int wflag = *wflagp;
  const int tid  = threadIdx.x;
  const int lane = tid & 63;
  const int w    = tid >> 6;
  const int wm   = w >> 1;
  const int wn   = w & 1;

  const int gx = gridDim.x;
  int wg = blockIdx.x + gx * blockIdx.y;
  {
    const int nwg = gx * gridDim.y;
    const int q = nwg >> 3, r = nwg & 7;
    const int xcd = wg & 7;
    const int idx = wg >> 3;
    wg = (xcd < r ? xcd * (q + 1) : r * (q + 1) + (xcd - r) * q) + idx;
  }
  const int nt = wg % gx;
  const int mt = wg / gx;
  const int n0 = nt << 6;
  const int m0 = mt << 6;
  const int KSQ   = Fi >> 5;
  const int qsh   = __builtin_ctz(KSQ);
  const int qmask = KSQ - 1;
  const int KS    = NQ << qsh;

  const int laneoff = lane << 3;

  f32x16 acc = {};

#pragma unroll 2
  for (int ks = 0; ks < KS; ks++) {
    const int q   = ks >> qsh;
    const int ksl = ks & qmask;
    const u16* Ah = (q == 0) ? a0h : (q == 1 ? a1h : a2h);
    const u16* Al = (q == 0) ? a0l : (q == 1 ? a1l : a2l);
    const size_t abase = ((size_t)(mt * KSQ + ksl) << 2) * 512 + (size_t)((wm << 1) * 512) + laneoff;
    const bf16x8 aH0 = *(const bf16x8*)(Ah + abase);
    const bf16x8 aH1 = *(const bf16x8*)(Ah + abase + 512);
    const bf16x8 aL0 = *(const bf16x8*)(Al + abase);
    const bf16x8 aL1 = *(const bf16x8*)(Al + abase + 512);
    const size_t bbase = (((size_t)(nt * KS + ks) << 2) + (wn << 1)) * 512 + laneoff;
    const bf16x8 b0 = *(const bf16x8*)(packHi + bbase);
    const bf16x8 b1 = *(const bf16x8*)(packHi + bbase + 512);

    acc = __builtin_amdgcn_mfma_f32_32x32x16_bf16(aH0, b0, acc, 0, 0, 0);
    acc = __builtin_amdgcn_mfma_f32_32x32x16_bf16(aL0, b0, acc, 0, 0, 0);
    acc = __builtin_amdgcn_mfma_f32_32x32x16_bf16(aH1, b1, acc, 0, 0, 0);
    acc = __builtin_amdgcn_mfma_f32_32x32x16_bf16(aL1, b1, acc, 0, 0, 0);
    if (wflag) {
      const bf16x8 c0 = *(const bf16x8*)(packLo + bbase);
      const bf16x8 c1 = *(const bf16x8*)(packLo + bbase + 512);
      acc = __builtin_amdgcn_mfma_f32_32x32x16_bf16(aH0, c0, acc, 0, 0, 0);
      acc = __builtin_amdgcn_mfma_f32_32x32x16_bf16(aH1, c1, acc, 0, 0, 0);
    }
  }

  {
    const int ncol = n0 + (wn << 5) + (lane & 31);
    const int KSQo = Fo >> 5;
    int col = ncol;
    const void* bp = bias;
    size_t obase = 0;
    int FoOut = Fo;
    if (headSplit) {
      FoOut = 256;
      if (ncol >= 256) { col = ncol - 256; bp = bias2; obase = (size_t)N * 256; }
    }
    const float bv = wflag ? ((const float*)bp)[col]
                           : bf2f(((const u16*)bp)[col]);
#pragma unroll
    for (int r = 0; r < 16; r++) {
      const int m = m0 + (wm << 5) + (r & 3) + ((r >> 2) << 3) + ((lane >> 5) << 2);
      if (m < N) {
        float vv = acc[r] + bv;
        if (relu) vv = fmaxf(vv, 0.f);
        if (outH) {
          u16 h = f2bf(vv);
          const size_t pi = apidx(m, ncol, KSQo);
          outH[pi] = h;
          outL[pi] = f2bf(vv - bf2f(h));
          if (outB) outB[(size_t)m * Fo + ncol] = h;   // row-major for props
        }
        if (outB16) {
          const size_t o = obase + (size_t)m * FoOut + col;
          if (wflag) outB32[o] = vv;
          else       outB16[o] = f2bf(vv);
        }
      }
    }
  }
}

// ---------------- host (kernel launches ONLY) ----------------

static size_t align256(size_t x) { return (x + 255) & ~(size_t)255; }

extern "C" void kernel_launch(void* const* d_in, const int* in_sizes, int n_in,
                              void* d_out, int out_size, void* d_ws, size_t ws_size,
                              hipStream_t stream) {
  const void* v    = d_in[0];
  const void* ei   = d_in[1];
  const void* W1   = d_in[2];
  const void* b1   = d_in[3];
  const void* W2   = d_in[4];
  const void* b2   = d_in[5];
  const void* W3   = d_in[6];
  const void* b3   = d_in[7];
  const void* Wmu  = d_in[8];
  const void* bmu  = d_in[9];
  const void* Wstd = d_in[10];
  const void* bstd = d_in[11];
  (void)n_in; (void)ws_size;

  const int N = in_sizes[0] / 128;   // 10000
  const int E = in_sizes[1] / 2;     // 160000
  const size_t NP = ((size_t)N + 63) & ~(size_t)63;

  char* base = (char*)d_ws;
  size_t off = 0;
  auto carve = [&](size_t bytes) { void* p = base + off; off = align256(off + bytes); return p; };

  int*   eflag  = (int*)  carve(4);      // flags[0]=eflag, flags[1]=vflag
  int*   vflag  = (int*)  carve(4);
  int*   rowi   = (int*)  carve((size_t)E * 4);
  int*   coli   = (int*)  carve((size_t)E * 4);
  float* deg    = (float*)carve((size_t)N * 4);
  float* dis    = (float*)carve((size_t)N * 4);
  int*   cnt    = (int*)  carve((size_t)N * 4);
  int*   colPtr = (int*)  carve((size_t)(N + 1) * 4);
  int*   cursor = (int*)  carve((size_t)N * 4);
  int2*  edges  = (int2*) carve((size_t)E * 8);

  u16* pW1h = (u16*)carve((size_t)384 * 128 * 2);
  u16* pW1l = (u16*)carve((size_t)384 * 128 * 2);
  u16* pW2h = (u16*)carve((size_t)384 * 256 * 2);
  u16* pW2l = (u16*)carve((size_t)384 * 256 * 2);
  u16* pW3h = (u16*)carve((size_t)768 * 512 * 2);
  u16* pW3l = (u16*)carve((size_t)768 * 512 * 2);
  u16* pHh  = (u16*)carve((size_t)2 * 512 * 256 * 2);
  u16* pHl  = (u16*)carve((size_t)2 * 512 * 256 * 2);

  // activation storage: bf16 row-major planes (prop gathers) + hi/lo packs (GEMM)
  u16* Xb  = (u16*)carve(NP * 256 * 2);   // layer input plane (F up to 256)
  u16* Xh  = (u16*)carve(NP * 256 * 2);
  u16* Xl  = (u16*)carve(NP * 256 * 2);
  u16* Yb  = (u16*)carve(NP * 128 * 2);   // L1 output plane (F=128)
  u16* Yh  = (u16*)carve(NP * 512 * 2);
  u16* Yl  = (u16*)carve(NP * 512 * 2);
  u16* t1b = (u16*)carve(NP * 256 * 2);
  u16* t1h = (u16*)carve(NP * 256 * 2);
  u16* t1l = (u16*)carve(NP * 256 * 2);
  u16* t2h = (u16*)carve(NP * 256 * 2);
  u16* t2l = (u16*)carve(NP * 256 * 2);

  // 1) fused probes + zero + sentinel
  const int zb = (N + 255) / 256;
  const int sb = (out_size + 255) / 256;
  k_init<<<2 + zb + sb, 256, 0, stream>>>((const unsigned*)v, 1024, vflag,
                                          (const unsigned*)ei, 2048, eflag,
                                          deg, cnt, N, zb, (u16*)d_out, out_size);

  // 2) fused weight packs + input convert
  const int n4 = N * 128 / 4;
  const int c1 = 24, c2 = c1 + 48, c3 = c2 + 192, c4 = c3 + 64, c5 = c4 + 64;
  const int cTot = c5 + (n4 + 255) / 256;
  k_pack<<<cTot, 256, 0, stream>>>(W1, W2, W3, Wmu, Wstd,
                                   pW1h, pW1l, pW2h, pW2l, pW3h, pW3l, pHh, pHl,
                                   v, Xb, Xh, Xl, n4, eflag,
                                   c1, c2, c3, c4, c5);

  // 3) graph preprocessing
  k_decode<<<(E + 255) / 256, 256, 0, stream>>>(ei, eflag, E, N, rowi, coli, deg, cnt);
  k_scan<<<1, 1024, 0, stream>>>(cnt, colPtr, cursor, deg, dis, N);
  k_place<<<(E + 255) / 256, 256, 0, stream>>>(rowi, coli, dis, cursor, edges, E);

  const int gM = (N + 63) / 64;
  const int gP = (N + 3) / 4;

  // layer 1: Fi=128 -> Fo=128, X -> Y
  k_prop128<<<gP, 256, 0, stream>>>(Xb, nullptr, t1b, t1h, t1l, colPtr, edges, N, 1.f, 0.f);
  k_prop128<<<gP, 256, 0, stream>>>(t1b, Xb, nullptr, t2h, t2l, colPtr, edges, N, 2.f, -1.f);
  k_gemm_mfma<<<dim3(2, gM), 256, 0, stream>>>(Xh, Xl, t1h, t1l, t2h, t2l, pW1h, pW1l,
                                               b1, b1, vflag, N, 128, 3, 128,
                                               Yb, Yh, Yl, nullptr, nullptr, 1, 0);

  // layer 2: Fi=128 -> Fo=256, Y -> X
  k_prop128<<<gP, 256, 0, stream>>>(Yb, nullptr, t1b, t1h, t1l, colPtr, edges, N, 1.f, 0.f);
  k_prop128<<<gP, 256, 0, stream>>>(t1b, Yb, nullptr, t2h, t2l, colPtr, edges, N, 2.f, -1.f);
  k_gemm_mfma<<<dim3(4, gM), 256, 0, stream>>>(Yh, Yl, t1h, t1l, t2h, t2l, pW2h, pW2l,
                                               b2, b2, vflag, N, 128, 3, 256,
                                               Xb, Xh, Xl, nullptr, nullptr, 1, 0);

  // layer 3: Fi=256 -> Fo=512, X -> Y (packs only; heads is the only consumer)
  k_prop256<<<gP, 256, 0, stream>>>(Xb, nullptr, t1b, t1h, t1l, colPtr, edges, N, 1.f, 0.f);
  k_prop256<<<gP, 256, 0, stream>>>(t1b, Xb, nullptr, t2h, t2l, colPtr, edges, N, 2.f, -1.f);
  k_gemm_mfma<<<dim3(8, gM), 256, 0, stream>>>(Xh, Xl, t1h, t1l, t2h, t2l, pW3h, pW3l,
                                               b3, b3, vflag, N, 256, 3, 512,
                                               nullptr, Yh, Yl, nullptr, nullptr, 1, 0);

  // fused heads
  k_gemm_mfma<<<dim3(8, gM), 256, 0, stream>>>(Yh, Yl, nullptr, nullptr, nullptr, nullptr,
                                               pHh, pHl, bmu, bstd, vflag, N, 512, 1, 512,
                                               nullptr, nullptr, nullptr,
                                               (u16*)d_out, (float*)d_out, 0, 1);
}

// Round 12
// 291.984 us; speedup vs baseline: 1.1853x; 1.0761x over previous
//
#include <hip/hip_runtime.h>
#include <hip/hip_bf16.h>

// ---------------- types & helpers ----------------

typedef __attribute__((ext_vector_type(8)))  short bf16x8;   // 8 bf16 = 4 VGPR
typedef __attribute__((ext_vector_type(16))) float f32x16;   // MFMA 32x32 acc
typedef unsigned short u16;

__device__ __forceinline__ u16 f2bf(float x) {               // RNE fp32->bf16
  union { float f; unsigned u; } c; c.f = x;
  return (u16)((c.u + 0x7fffu + ((c.u >> 16) & 1u)) >> 16);
}
__device__ __forceinline__ float bf2f(u16 u) {               // exact bf16->fp32
  union { unsigned u; float f; } c; c.u = ((unsigned)u) << 16;
  return c.f;
}

// A-pack addressing (fragment-linear, 64-row m-tiles, 32-k ksteps).
// Element (row r, col k), KSQ = Fi/32:
//   slot = ((r>>6)*KSQ + (k>>5))*4 + ((r>>5)&1)*2 + ((k>>4)&1)
//   lane = (r&31) + ((k>>3)&1)*32 ;  j = k&7 ;  idx = slot*512 + lane*8 + j
__device__ __forceinline__ size_t apidx(int r, int k, int KSQ) {
  const int slot = (((r >> 6) * KSQ + (k >> 5)) << 2) + (((r >> 5) & 1) << 1) + ((k >> 4) & 1);
  return ((size_t)slot << 9) + (size_t)(((((k >> 3) & 1) << 5) | (r & 31)) << 3) + (k & 7);
}

// ---------------- fused init: dtype probes + zero + sentinel ----------------
__global__ void k_init(const unsigned* __restrict__ v, int nv, int* __restrict__ vflag,
                       const unsigned* __restrict__ ei, int ne, int* __restrict__ eflag,
                       float* __restrict__ deg, int* __restrict__ cnt, int n, int zb,
                       u16* __restrict__ outSent, int outN) {
  __shared__ unsigned red[256];
  if (blockIdx.x == 0) {
    int ok = 0;
    for (int i = threadIdx.x; i < nv; i += 256) {
      unsigned lo = v[i] & 0xffffu;
      unsigned ef = (lo >> 7) & 0xffu;
      if (ef >= 115u && ef <= 140u) ok++;
    }
    red[threadIdx.x] = (unsigned)ok;
    __syncthreads();
    for (int s = 128; s > 0; s >>= 1) {
      if (threadIdx.x < s) red[threadIdx.x] += red[threadIdx.x + s];
      __syncthreads();
    }
    if (threadIdx.x == 0) *vflag = ((int)red[0] < nv / 2) ? 1 : 0;
  } else if (blockIdx.x == 1) {
    unsigned acc = 0;
    for (int i = threadIdx.x; i < ne; i += 256)
      if (i & 1) acc |= ei[i];
    red[threadIdx.x] = acc;
    __syncthreads();
    for (int s = 128; s > 0; s >>= 1) {
      if (threadIdx.x < s) red[threadIdx.x] |= red[threadIdx.x + s];
      __syncthreads();
    }
    if (threadIdx.x == 0) *eflag = (red[0] == 0u) ? 1 : 0;
  } else if (blockIdx.x < 2 + zb) {
    int i = (blockIdx.x - 2) * 256 + threadIdx.x;
    if (i < n) { deg[i] = 0.0f; cnt[i] = 0; }
  } else {
    int i = (blockIdx.x - 2 - zb) * 256 + threadIdx.x;
    if (i < outN) outSent[i] = 0x3F00;
  }
}

// ---------------- fused pack: 5 weight packs + input convert ----------------
__device__ __forceinline__ void wpack_dev(
    const void* __restrict__ W, int wflag, int K, int Fo,
    u16* __restrict__ dstHi, u16* __restrict__ dstLo, int blk, int tid) {
  const int t = blk * 256 + tid;
  const int KS = K >> 5;
  const int total = (Fo >> 6) * KS * 4;
  const int s = t >> 6;
  if (s >= total) return;
  const int lane = t & 63;
  const int fb = s & 3;
  const int sk = s >> 2;
  const int ks = sk % KS;
  const int nt = sk / KS;
  const int col = (nt << 6) + ((fb >> 1) << 5) + (lane & 31);
  const int row = (ks << 5) + ((fb & 1) << 4) + ((lane >> 5) << 3);
  bf16x8 hi;
  if (wflag) {
    const float* Wf = (const float*)W;
    bf16x8 lo;
#pragma unroll
    for (int j = 0; j < 8; j++) {
      float wv = Wf[(size_t)(row + j) * Fo + col];
      u16 h = f2bf(wv);
      hi[j] = (short)h;
      lo[j] = (short)f2bf(wv - bf2f(h));
    }
    *(bf16x8*)(dstLo + (size_t)s * 512 + lane * 8) = lo;
  } else {
    const u16* Wb = (const u16*)W;
#pragma unroll
    for (int j = 0; j < 8; j++)
      hi[j] = (short)Wb[(size_t)(row + j) * Fo + col];
  }
  *(bf16x8*)(dstHi + (size_t)s * 512 + lane * 8) = hi;
}

__global__ void k_pack(const void* __restrict__ W1, const void* __restrict__ W2,
                       const void* __restrict__ W3, const void* __restrict__ Wmu,
                       const void* __restrict__ Wstd,
                       u16* pW1h, u16* pW1l, u16* pW2h, u16* pW2l,
                       u16* pW3h, u16* pW3l, u16* pHh, u16* pHl,
                       const void* __restrict__ v, u16* __restrict__ xb,
                       u16* __restrict__ xh, int n4,
                       const int* __restrict__ flags,
                       int c1, int c2, int c3, int c4, int c5) {
  const int wflag = flags[1];   // vflag (weights share input dtype)
  const int b = blockIdx.x;
  const int tid = threadIdx.x;
  if (b < c1)      { wpack_dev(W1,   wflag, 384, 128, pW1h, pW1l, b,      tid); return; }
  if (b < c2)      { wpack_dev(W2,   wflag, 384, 256, pW2h, pW2l, b - c1, tid); return; }
  if (b < c3)      { wpack_dev(W3,   wflag, 768, 512, pW3h, pW3l, b - c2, tid); return; }
  if (b < c4)      { wpack_dev(Wmu,  wflag, 512, 256, pHh,           pHl,           b - c3, tid); return; }
  if (b < c5)      { wpack_dev(Wstd, wflag, 512, 256, pHh + 131072,  pHl + 131072,  b - c4, tid); return; }
  const int i = (b - c5) * 256 + tid;
  if (i >= n4) return;
  float val[4];
  if (wflag) {
    float4 t = ((const float4*)v)[i];
    val[0] = t.x; val[1] = t.y; val[2] = t.z; val[3] = t.w;
  } else {
    ushort4 t = ((const ushort4*)v)[i];
    val[0] = bf2f(t.x); val[1] = bf2f(t.y); val[2] = bf2f(t.z); val[3] = bf2f(t.w);
  }
  ushort4 ho;
  ho.x = f2bf(val[0]); ho.y = f2bf(val[1]);
  ho.z = f2bf(val[2]); ho.w = f2bf(val[3]);
  *(ushort4*)(xb + (size_t)i * 4) = ho;      // bf16 row-major plane (prop input)
  const int r  = i >> 5;
  const int k0 = (i & 31) << 2;
  const size_t pi = apidx(r, k0, 4);
  *(ushort4*)(xh + pi) = ho;                 // A-pack hi (GEMM)
}

// ---------------- preprocessing ----------------

__global__ void k_decode(const void* __restrict__ ei, const int* __restrict__ eflag,
                         int E, int N, int* __restrict__ rowi, int* __restrict__ coli,
                         float* __restrict__ deg, int* __restrict__ cnt) {
  int e = blockIdx.x * blockDim.x + threadIdx.x;
  if (e >= E) return;
  int f = *eflag;
  int r, c;
  if (f) {
    const long long* q = (const long long*)ei;
    r = (int)q[e]; c = (int)q[e + E];
  } else {
    const int* q = (const int*)ei;
    r = q[e]; c = q[e + E];
  }
  r = min(max(r, 0), N - 1);
  c = min(max(c, 0), N - 1);
  rowi[e] = r; coli[e] = c;
  atomicAdd(&deg[r], 1.0f);
  atomicAdd(&cnt[c], 1);
}

// 1024-thread shuffle scan fused with dis = rsqrt(deg)
__global__ __launch_bounds__(1024) void k_scan(const int* __restrict__ cnt,
                                               int* __restrict__ colPtr,
                                               int* __restrict__ cursor,
                                               const float* __restrict__ deg,
                                               float* __restrict__ dis, int n) {
  __shared__ int ws[16];
  const int t = threadIdx.x;
  const int lane = t & 63;
  const int w = t >> 6;
  int carry = 0;
  for (int base = 0; base < n; base += 1024) {
    int i = base + t;
    int v = (i < n) ? cnt[i] : 0;
    if (i < n) {
      float d = deg[i];
      dis[i] = (d > 0.f) ? rsqrtf(d) : 0.f;
    }
    int x = v;
#pragma unroll
    for (int off = 1; off < 64; off <<= 1) {
      int y = __shfl_up(x, off);
      if (lane >= off) x += y;
    }
    if (lane == 63) ws[w] = x;
    __syncthreads();
    if (w == 0) {
      int sv = (lane < 16) ? ws[lane] : 0;
#pragma unroll
      for (int off = 1; off < 16; off <<= 1) {
        int y = __shfl_up(sv, off);
        if (lane >= off) sv += y;
      }
      if (lane < 16) ws[lane] = sv;
    }
    __syncthreads();
    int woff = (w == 0) ? 0 : ws[w - 1];
    int incl = carry + woff + x;
    if (i < n) { colPtr[i + 1] = incl; cursor[i] = incl - v; }
    int tot = ws[15];
    __syncthreads();
    carry += tot;
  }
  if (t == 0) colPtr[0] = 0;
}

// place: CSC edge list as packed int2 {srcRow, w-bits}
__global__ void k_place(const int* __restrict__ rowi, const int* __restrict__ coli,
                        const float* __restrict__ dis, int* __restrict__ cursor,
                        int2* __restrict__ edges, int E) {
  int e = blockIdx.x * blockDim.x + threadIdx.x;
  if (e >= E) return;
  int r = rowi[e], c = coli[e];
  float wv = -dis[r] * dis[c];
  int pos = atomicAdd(&cursor[c], 1);
  edges[pos] = make_int2(r, __float_as_int(wv));
}

// ---------------- propagation F=128 (bf16 gather, wave-per-node) ----------------
// bf16 row gathers (traffic-bound; r11 confirmed -32us from halved bytes).
// hi-only output (r12: layer GEMMs drop the A-lo correction).
__global__ __launch_bounds__(256) void k_prop128(
    const u16* __restrict__ z, const u16* __restrict__ base,
    u16* __restrict__ outB, u16* __restrict__ outH,
    const int* __restrict__ colPtr, const int2* __restrict__ edges,
    int N, float alpha, float beta) {
  const int lane = threadIdx.x & 63;
  const int c = blockIdx.x * 4 + (threadIdx.x >> 6);
  if (c >= N) return;
  const int half = lane >> 5;
  const int li = lane & 31;
  const int s = colPtr[c], e = colPtr[c + 1];
  float4 acc[4];
#pragma unroll
  for (int k = 0; k < 4; k++) acc[k] = make_float4(0.f, 0.f, 0.f, 0.f);

  for (int j0 = s; j0 < e; j0 += 64) {
    const int take = min(64, e - j0);
    int rI = 0; float wI = 0.f;
    if (j0 + lane < e) {
      int2 ew = edges[j0 + lane];
      rI = ew.x; wI = __int_as_float(ew.y);
    }
    for (int jj = 0; jj < take; jj += 32) {
      int rr[16]; float ww[16];
#pragma unroll
      for (int p = 0; p < 16; p++) {
        rr[p] = __shfl(rI, jj + 2 * p + half);
        ww[p] = __shfl(wI, jj + 2 * p + half);
      }
      ushort4 zz[16];
#pragma unroll
      for (int p = 0; p < 16; p++)
        zz[p] = *(const ushort4*)(z + (size_t)rr[p] * 128 + li * 4);
#pragma unroll
      for (int p = 0; p < 16; p++) {
        const float wk = ww[p];
        acc[p & 3].x = fmaf(wk, bf2f(zz[p].x), acc[p & 3].x);
        acc[p & 3].y = fmaf(wk, bf2f(zz[p].y), acc[p & 3].y);
        acc[p & 3].z = fmaf(wk, bf2f(zz[p].z), acc[p & 3].z);
        acc[p & 3].w = fmaf(wk, bf2f(zz[p].w), acc[p & 3].w);
      }
    }
  }

  float4 a;
  a.x = (acc[0].x + acc[1].x) + (acc[2].x + acc[3].x);
  a.y = (acc[0].y + acc[1].y) + (acc[2].y + acc[3].y);
  a.z = (acc[0].z + acc[1].z) + (acc[2].z + acc[3].z);
  a.w = (acc[0].w + acc[1].w) + (acc[2].w + acc[3].w);
  a.x += __shfl_xor(a.x, 32);
  a.y += __shfl_xor(a.y, 32);
  a.z += __shfl_xor(a.z, 32);
  a.w += __shfl_xor(a.w, 32);

  if (lane < 32) {
    float vv[4] = {alpha * a.x, alpha * a.y, alpha * a.z, alpha * a.w};
    const size_t o = (size_t)c * 128 + li * 4;
    if (base != nullptr) {
      ushort4 b = *(const ushort4*)(base + o);
      vv[0] = fmaf(beta, bf2f(b.x), vv[0]); vv[1] = fmaf(beta, bf2f(b.y), vv[1]);
      vv[2] = fmaf(beta, bf2f(b.z), vv[2]); vv[3] = fmaf(beta, bf2f(b.w), vv[3]);
    }
    ushort4 ho;
    ho.x = f2bf(vv[0]); ho.y = f2bf(vv[1]);
    ho.z = f2bf(vv[2]); ho.w = f2bf(vv[3]);
    if (outB) *(ushort4*)(outB + o) = ho;     // bf16 row-major (next prop)
    const size_t pi = apidx(c, li << 2, 4);   // A-pack hi, Fi=128 (GEMM)
    *(ushort4*)(outH + pi) = ho;
  }
}

// ---------------- propagation F=256 (bf16 gather, wave-per-node) ----------------
__global__ __launch_bounds__(256) void k_prop256(
    const u16* __restrict__ z, const u16* __restrict__ base,
    u16* __restrict__ outB, u16* __restrict__ outH,
    const int* __restrict__ colPtr, const int2* __restrict__ edges,
    int N, float alpha, float beta) {
  const int lane = threadIdx.x & 63;
  const int c = blockIdx.x * 4 + (threadIdx.x >> 6);
  if (c >= N) return;
  const int s = colPtr[c], e = colPtr[c + 1];
  float4 acc[4];
#pragma unroll
  for (int k = 0; k < 4; k++) acc[k] = make_float4(0.f, 0.f, 0.f, 0.f);

  for (int j0 = s; j0 < e; j0 += 64) {
    const int take = min(64, e - j0);
    int rI = 0; float wI = 0.f;
    if (j0 + lane < e) {
      int2 ew = edges[j0 + lane];
      rI = ew.x; wI = __int_as_float(ew.y);
    }
    for (int jj = 0; jj < take; jj += 16) {
      int rr[16]; float ww[16];
#pragma unroll
      for (int k = 0; k < 16; k++) {
        rr[k] = __shfl(rI, jj + k);
        ww[k] = __shfl(wI, jj + k);
      }
      ushort4 zz[16];
#pragma unroll
      for (int k = 0; k < 16; k++)
        zz[k] = *(const ushort4*)(z + (size_t)rr[k] * 256 + lane * 4);
#pragma unroll
      for (int k = 0; k < 16; k++) {
        const float wk = ww[k];
        acc[k & 3].x = fmaf(wk, bf2f(zz[k].x), acc[k & 3].x);
        acc[k & 3].y = fmaf(wk, bf2f(zz[k].y), acc[k & 3].y);
        acc[k & 3].z = fmaf(wk, bf2f(zz[k].z), acc[k & 3].z);
        acc[k & 3].w = fmaf(wk, bf2f(zz[k].w), acc[k & 3].w);
      }
    }
  }

  float vv[4] = {alpha * ((acc[0].x + acc[1].x) + (acc[2].x + acc[3].x)),
                 alpha * ((acc[0].y + acc[1].y) + (acc[2].y + acc[3].y)),
                 alpha * ((acc[0].z + acc[1].z) + (acc[2].z + acc[3].z)),
                 alpha * ((acc[0].w + acc[1].w) + (acc[2].w + acc[3].w))};
  const size_t o = (size_t)c * 256 + lane * 4;
  if (base != nullptr) {
    ushort4 b = *(const ushort4*)(base + o);
    vv[0] = fmaf(beta, bf2f(b.x), vv[0]); vv[1] = fmaf(beta, bf2f(b.y), vv[1]);
    vv[2] = fmaf(beta, bf2f(b.z), vv[2]); vv[3] = fmaf(beta, bf2f(b.w), vv[3]);
  }
  ushort4 ho;
  ho.x = f2bf(vv[0]); ho.y = f2bf(vv[1]);
  ho.z = f2bf(vv[2]); ho.w = f2bf(vv[3]);
  if (outB) *(ushort4*)(outB + o) = ho;
  const size_t pi = apidx(c, lane << 2, 8);    // A-pack hi, Fi=256
  *(ushort4*)(outH + pi) = ho;
}

// ---------------- MFMA GEMM (LDS-free, barrier-free, XCD swizzle) ----------------
// A-lo correction is OPTIONAL (a0l == nullptr -> skip): layer GEMMs run pure
// bf16 (half the loads+MFMAs); heads keep exact hi/lo x3 (final accuracy).
// wflag (fp32 weights) keeps the B-lo correction.
// C/D mapping (verified): col = lane&31, row = (reg&3)+8*(reg>>2)+4*(lane>>5).
__global__ __launch_bounds__(256, 4) void k_gemm_mfma(
    const u16* __restrict__ a0h, const u16* __restrict__ a0l,
    const u16* __restrict__ a1h, const u16* __restrict__ a1l,
    const u16* __restrict__ a2h, const u16* __restrict__ a2l,
    const u16* __restrict__ packHi, const u16* __restrict__ packLo,
    const void* __restrict__ bias, const void* __restrict__ bias2,
    const int* __restrict__ wflagp,
    int N, int Fi, int NQ, int Fo,
    u16* __restrict__ outB, u16* __restrict__ outH, u16* __restrict__ outL,
    u16* __restrict__ outB16, float* __restrict__ outB32, int relu, int headSplit) {
  const int wflag = *wflagp;
  const bool useLo = (a0l != nullptr);
  const int tid  = threadIdx.x;
  const int lane = tid & 63;
  const int w    = tid >> 6;
  const int wm   = w >> 1;
  const int wn   = w & 1;

  const int gx = gridDim.x;
  int wg = blockIdx.x + gx * blockIdx.y;
  {
    const int nwg = gx * gridDim.y;
    const int q = nwg >> 3, r = nwg & 7;
    const int xcd = wg & 7;
    const int idx = wg >> 3;
    wg = (xcd < r ? xcd * (q + 1) : r * (q + 1) + (xcd - r) * q) + idx;
  }
  const int nt = wg % gx;
  const int mt = wg / gx;
  const int n0 = nt << 6;
  const int m0 = mt << 6;
  const int KSQ   = Fi >> 5;
  const int qsh   = __builtin_ctz(KSQ);
  const int qmask = KSQ - 1;
  const int KS    = NQ << qsh;

  const int laneoff = lane << 3;

  f32x16 acc = {};

#pragma unroll 2
  for (int ks = 0; ks < KS; ks++) {
    const int q   = ks >> qsh;
    const int ksl = ks & qmask;
    const u16* Ah = (q == 0) ? a0h : (q == 1 ? a1h : a2h);
    const size_t abase = ((size_t)(mt * KSQ + ksl) << 2) * 512 + (size_t)((wm << 1) * 512) + laneoff;
    const bf16x8 aH0 = *(const bf16x8*)(Ah + abase);
    const bf16x8 aH1 = *(const bf16x8*)(Ah + abase + 512);
    const size_t bbase = (((size_t)(nt * KS + ks) << 2) + (wn << 1)) * 512 + laneoff;
    const bf16x8 b0 = *(const bf16x8*)(packHi + bbase);
    const bf16x8 b1 = *(const bf16x8*)(packHi + bbase + 512);

    acc = __builtin_amdgcn_mfma_f32_32x32x16_bf16(aH0, b0, acc, 0, 0, 0);
    acc = __builtin_amdgcn_mfma_f32_32x32x16_bf16(aH1, b1, acc, 0, 0, 0);
    if (useLo) {
      const u16* Al = (q == 0) ? a0l : (q == 1 ? a1l : a2l);
      const bf16x8 aL0 = *(const bf16x8*)(Al + abase);
      const bf16x8 aL1 = *(const bf16x8*)(Al + abase + 512);
      acc = __builtin_amdgcn_mfma_f32_32x32x16_bf16(aL0, b0, acc, 0, 0, 0);
      acc = __builtin_amdgcn_mfma_f32_32x32x16_bf16(aL1, b1, acc, 0, 0, 0);
    }
    if (wflag) {
      const bf16x8 c0 = *(const bf16x8*)(packLo + bbase);
      const bf16x8 c1 = *(const bf16x8*)(packLo + bbase + 512);
      acc = __builtin_amdgcn_mfma_f32_32x32x16_bf16(aH0, c0, acc, 0, 0, 0);
      acc = __builtin_amdgcn_mfma_f32_32x32x16_bf16(aH1, c1, acc, 0, 0, 0);
    }
  }

  {
    const int ncol = n0 + (wn << 5) + (lane & 31);
    const int KSQo = Fo >> 5;
    int col = ncol;
    const void* bp = bias;
    size_t obase = 0;
    int FoOut = Fo;
    if (headSplit) {
      FoOut = 256;
      if (ncol >= 256) { col = ncol - 256; bp = bias2; obase = (size_t)N * 256; }
    }
    const float bv = wflag ? ((const float*)bp)[col]
                           : bf2f(((const u16*)bp)[col]);
#pragma unroll
    for (int r = 0; r < 16; r++) {
      const int m = m0 + (wm << 5) + (r & 3) + ((r >> 2) << 3) + ((lane >> 5) << 2);
      if (m < N) {
        float vv = acc[r] + bv;
        if (relu) vv = fmaxf(vv, 0.f);
        if (outH) {
          u16 h = f2bf(vv);
          const size_t pi = apidx(m, ncol, KSQo);
          outH[pi] = h;
          if (outL) outL[pi] = f2bf(vv - bf2f(h));   // only L3 (heads operand)
          if (outB) outB[(size_t)m * Fo + ncol] = h; // row-major for props
        }
        if (outB16) {
          const size_t o = obase + (size_t)m * FoOut + col;
          if (wflag) outB32[o] = vv;
          else       outB16[o] = f2bf(vv);
        }
      }
    }
  }
}

// ---------------- host (kernel launches ONLY) ----------------

static size_t align256(size_t x) { return (x + 255) & ~(size_t)255; }

extern "C" void kernel_launch(void* const* d_in, const int* in_sizes, int n_in,
                              void* d_out, int out_size, void* d_ws, size_t ws_size,
                              hipStream_t stream) {
  const void* v    = d_in[0];
  const void* ei   = d_in[1];
  const void* W1   = d_in[2];
  const void* b1   = d_in[3];
  const void* W2   = d_in[4];
  const void* b2   = d_in[5];
  const void* W3   = d_in[6];
  const void* b3   = d_in[7];
  const void* Wmu  = d_in[8];
  const void* bmu  = d_in[9];
  const void* Wstd = d_in[10];
  const void* bstd = d_in[11];
  (void)n_in; (void)ws_size;

  const int N = in_sizes[0] / 128;   // 10000
  const int E = in_sizes[1] / 2;     // 160000
  const size_t NP = ((size_t)N + 63) & ~(size_t)63;

  char* base = (char*)d_ws;
  size_t off = 0;
  auto carve = [&](size_t bytes) { void* p = base + off; off = align256(off + bytes); return p; };

  int*   eflag  = (int*)  carve(4);      // flags[0]=eflag, flags[1]=vflag
  int*   vflag  = (int*)  carve(4);
  int*   rowi   = (int*)  carve((size_t)E * 4);
  int*   coli   = (int*)  carve((size_t)E * 4);
  float* deg    = (float*)carve((size_t)N * 4);
  float* dis    = (float*)carve((size_t)N * 4);
  int*   cnt    = (int*)  carve((size_t)N * 4);
  int*   colPtr = (int*)  carve((size_t)(N + 1) * 4);
  int*   cursor = (int*)  carve((size_t)N * 4);
  int2*  edges  = (int2*) carve((size_t)E * 8);

  u16* pW1h = (u16*)carve((size_t)384 * 128 * 2);
  u16* pW1l = (u16*)carve((size_t)384 * 128 * 2);
  u16* pW2h = (u16*)carve((size_t)384 * 256 * 2);
  u16* pW2l = (u16*)carve((size_t)384 * 256 * 2);
  u16* pW3h = (u16*)carve((size_t)768 * 512 * 2);
  u16* pW3l = (u16*)carve((size_t)768 * 512 * 2);
  u16* pHh  = (u16*)carve((size_t)2 * 512 * 256 * 2);
  u16* pHl  = (u16*)carve((size_t)2 * 512 * 256 * 2);

  // activation storage: bf16 row-major planes (prop gathers) + hi packs (GEMM)
  u16* Xb  = (u16*)carve(NP * 256 * 2);
  u16* Xh  = (u16*)carve(NP * 256 * 2);
  u16* Yb  = (u16*)carve(NP * 128 * 2);
  u16* Yh  = (u16*)carve(NP * 512 * 2);
  u16* Yl  = (u16*)carve(NP * 512 * 2);    // x3 lo (heads operand, exact)
  u16* t1b = (u16*)carve(NP * 256 * 2);
  u16* t1h = (u16*)carve(NP * 256 * 2);
  u16* t2h = (u16*)carve(NP * 256 * 2);

  // 1) fused probes + zero + sentinel
  const int zb = (N + 255) / 256;
  const int sb = (out_size + 255) / 256;
  k_init<<<2 + zb + sb, 256, 0, stream>>>((const unsigned*)v, 1024, vflag,
                                          (const unsigned*)ei, 2048, eflag,
                                          deg, cnt, N, zb, (u16*)d_out, out_size);

  // 2) fused weight packs + input convert
  const int n4 = N * 128 / 4;
  const int c1 = 24, c2 = c1 + 48, c3 = c2 + 192, c4 = c3 + 64, c5 = c4 + 64;
  const int cTot = c5 + (n4 + 255) / 256;
  k_pack<<<cTot, 256, 0, stream>>>(W1, W2, W3, Wmu, Wstd,
                                   pW1h, pW1l, pW2h, pW2l, pW3h, pW3l, pHh, pHl,
                                   v, Xb, Xh, n4, eflag,
                                   c1, c2, c3, c4, c5);

  // 3) graph preprocessing
  k_decode<<<(E + 255) / 256, 256, 0, stream>>>(ei, eflag, E, N, rowi, coli, deg, cnt);
  k_scan<<<1, 1024, 0, stream>>>(cnt, colPtr, cursor, deg, dis, N);
  k_place<<<(E + 255) / 256, 256, 0, stream>>>(rowi, coli, dis, cursor, edges, E);

  const int gM = (N + 63) / 64;
  const int gP = (N + 3) / 4;

  // layer 1: Fi=128 -> Fo=128, X -> Y (hi-only GEMM)
  k_prop128<<<gP, 256, 0, stream>>>(Xb, nullptr, t1b, t1h, colPtr, edges, N, 1.f, 0.f);
  k_prop128<<<gP, 256, 0, stream>>>(t1b, Xb, nullptr, t2h, colPtr, edges, N, 2.f, -1.f);
  k_gemm_mfma<<<dim3(2, gM), 256, 0, stream>>>(Xh, nullptr, t1h, nullptr, t2h, nullptr,
                                               pW1h, pW1l, b1, b1, vflag, N, 128, 3, 128,
                                               Yb, Yh, nullptr, nullptr, nullptr, 1, 0);

  // layer 2: Fi=128 -> Fo=256, Y -> X (hi-only GEMM)
  k_prop128<<<gP, 256, 0, stream>>>(Yb, nullptr, t1b, t1h, colPtr, edges, N, 1.f, 0.f);
  k_prop128<<<gP, 256, 0, stream>>>(t1b, Yb, nullptr, t2h, colPtr, edges, N, 2.f, -1.f);
  k_gemm_mfma<<<dim3(4, gM), 256, 0, stream>>>(Yh, nullptr, t1h, nullptr, t2h, nullptr,
                                               pW2h, pW2l, b2, b2, vflag, N, 128, 3, 256,
                                               Xb, Xh, nullptr, nullptr, nullptr, 1, 0);

  // layer 3: Fi=256 -> Fo=512, X -> Y (hi-only GEMM; emits hi+lo packs for heads)
  k_prop256<<<gP, 256, 0, stream>>>(Xb, nullptr, t1b, t1h, colPtr, edges, N, 1.f, 0.f);
  k_prop256<<<gP, 256, 0, stream>>>(t1b, Xb, nullptr, t2h, colPtr, edges, N, 2.f, -1.f);
  k_gemm_mfma<<<dim3(8, gM), 256, 0, stream>>>(Xh, nullptr, t1h, nullptr, t2h, nullptr,
                                               pW3h, pW3l, b3, b3, vflag, N, 256, 3, 512,
                                               nullptr, Yh, Yl, nullptr, nullptr, 1, 0);

  // fused heads: exact hi/lo x3 operand (final accuracy hedge)
  k_gemm_mfma<<<dim3(8, gM), 256, 0, stream>>>(Yh, Yl, nullptr, nullptr, nullptr, nullptr,
                                               pHh, pHl, bmu, bstd, vflag, N, 512, 1, 512,
                                               nullptr, nullptr, nullptr,
                                               (u16*)d_out, (float*)d_out, 0, 1);
}

// Round 13
// 272.141 us; speedup vs baseline: 1.2717x; 1.0729x over previous
//
#include <hip/hip_runtime.h>
#include <hip/hip_bf16.h>

// ---------------- types & helpers ----------------

typedef __attribute__((ext_vector_type(8)))  short bf16x8;   // 8 bf16 = 4 VGPR
typedef __attribute__((ext_vector_type(16))) float f32x16;   // MFMA 32x32 acc
typedef unsigned short u16;

__device__ __forceinline__ u16 f2bf(float x) {               // RNE fp32->bf16
  union { float f; unsigned u; } c; c.f = x;
  return (u16)((c.u + 0x7fffu + ((c.u >> 16) & 1u)) >> 16);
}
__device__ __forceinline__ float bf2f(u16 u) {               // exact bf16->fp32
  union { unsigned u; float f; } c; c.u = ((unsigned)u) << 16;
  return c.f;
}

// A-pack addressing (fragment-linear, 64-row m-tiles, 32-k ksteps).
// Element (row r, col k), KSQ = Fi/32:
//   slot = ((r>>6)*KSQ + (k>>5))*4 + ((r>>5)&1)*2 + ((k>>4)&1)
//   lane = (r&31) + ((k>>3)&1)*32 ;  j = k&7 ;  idx = slot*512 + lane*8 + j
__device__ __forceinline__ size_t apidx(int r, int k, int KSQ) {
  const int slot = (((r >> 6) * KSQ + (k >> 5)) << 2) + (((r >> 5) & 1) << 1) + ((k >> 4) & 1);
  return ((size_t)slot << 9) + (size_t)(((((k >> 3) & 1) << 5) | (r & 31)) << 3) + (k & 7);
}

// ---------------- fused init: dtype probes + zero + sentinel ----------------
__global__ void k_init(const unsigned* __restrict__ v, int nv, int* __restrict__ vflag,
                       const unsigned* __restrict__ ei, int ne, int* __restrict__ eflag,
                       float* __restrict__ deg, int* __restrict__ cnt, int n, int zb,
                       u16* __restrict__ outSent, int outN) {
  __shared__ unsigned red[256];
  if (blockIdx.x == 0) {
    int ok = 0;
    for (int i = threadIdx.x; i < nv; i += 256) {
      unsigned lo = v[i] & 0xffffu;
      unsigned ef = (lo >> 7) & 0xffu;
      if (ef >= 115u && ef <= 140u) ok++;
    }
    red[threadIdx.x] = (unsigned)ok;
    __syncthreads();
    for (int s = 128; s > 0; s >>= 1) {
      if (threadIdx.x < s) red[threadIdx.x] += red[threadIdx.x + s];
      __syncthreads();
    }
    if (threadIdx.x == 0) *vflag = ((int)red[0] < nv / 2) ? 1 : 0;
  } else if (blockIdx.x == 1) {
    unsigned acc = 0;
    for (int i = threadIdx.x; i < ne; i += 256)
      if (i & 1) acc |= ei[i];
    red[threadIdx.x] = acc;
    __syncthreads();
    for (int s = 128; s > 0; s >>= 1) {
      if (threadIdx.x < s) red[threadIdx.x] |= red[threadIdx.x + s];
      __syncthreads();
    }
    if (threadIdx.x == 0) *eflag = (red[0] == 0u) ? 1 : 0;
  } else if (blockIdx.x < 2 + zb) {
    int i = (blockIdx.x - 2) * 256 + threadIdx.x;
    if (i < n) { deg[i] = 0.0f; cnt[i] = 0; }
  } else {
    int i = (blockIdx.x - 2 - zb) * 256 + threadIdx.x;
    if (i < outN) outSent[i] = 0x3F00;
  }
}

// ---------------- fused pack: 5 weight packs + input convert ----------------
__device__ __forceinline__ void wpack_dev(
    const void* __restrict__ W, int wflag, int K, int Fo,
    u16* __restrict__ dstHi, u16* __restrict__ dstLo, int blk, int tid) {
  const int t = blk * 256 + tid;
  const int KS = K >> 5;
  const int total = (Fo >> 6) * KS * 4;
  const int s = t >> 6;
  if (s >= total) return;
  const int lane = t & 63;
  const int fb = s & 3;
  const int sk = s >> 2;
  const int ks = sk % KS;
  const int nt = sk / KS;
  const int col = (nt << 6) + ((fb >> 1) << 5) + (lane & 31);
  const int row = (ks << 5) + ((fb & 1) << 4) + ((lane >> 5) << 3);
  bf16x8 hi;
  if (wflag) {
    const float* Wf = (const float*)W;
    bf16x8 lo;
#pragma unroll
    for (int j = 0; j < 8; j++) {
      float wv = Wf[(size_t)(row + j) * Fo + col];
      u16 h = f2bf(wv);
      hi[j] = (short)h;
      lo[j] = (short)f2bf(wv - bf2f(h));
    }
    *(bf16x8*)(dstLo + (size_t)s * 512 + lane * 8) = lo;
  } else {
    const u16* Wb = (const u16*)W;
#pragma unroll
    for (int j = 0; j < 8; j++)
      hi[j] = (short)Wb[(size_t)(row + j) * Fo + col];
  }
  *(bf16x8*)(dstHi + (size_t)s * 512 + lane * 8) = hi;
}

__global__ void k_pack(const void* __restrict__ W1, const void* __restrict__ W2,
                       const void* __restrict__ W3, const void* __restrict__ Wmu,
                       const void* __restrict__ Wstd,
                       u16* pW1h, u16* pW1l, u16* pW2h, u16* pW2l,
                       u16* pW3h, u16* pW3l, u16* pHh, u16* pHl,
                       const void* __restrict__ v, u16* __restrict__ xb,
                       u16* __restrict__ xh, int n4,
                       const int* __restrict__ flags,
                       int c1, int c2, int c3, int c4, int c5) {
  const int wflag = flags[1];   // vflag (weights share input dtype)
  const int b = blockIdx.x;
  const int tid = threadIdx.x;
  if (b < c1)      { wpack_dev(W1,   wflag, 384, 128, pW1h, pW1l, b,      tid); return; }
  if (b < c2)      { wpack_dev(W2,   wflag, 384, 256, pW2h, pW2l, b - c1, tid); return; }
  if (b < c3)      { wpack_dev(W3,   wflag, 768, 512, pW3h, pW3l, b - c2, tid); return; }
  if (b < c4)      { wpack_dev(Wmu,  wflag, 512, 256, pHh,           pHl,           b - c3, tid); return; }
  if (b < c5)      { wpack_dev(Wstd, wflag, 512, 256, pHh + 131072,  pHl + 131072,  b - c4, tid); return; }
  const int i = (b - c5) * 256 + tid;
  if (i >= n4) return;
  float val[4];
  if (wflag) {
    float4 t = ((const float4*)v)[i];
    val[0] = t.x; val[1] = t.y; val[2] = t.z; val[3] = t.w;
  } else {
    ushort4 t = ((const ushort4*)v)[i];
    val[0] = bf2f(t.x); val[1] = bf2f(t.y); val[2] = bf2f(t.z); val[3] = bf2f(t.w);
  }
  ushort4 ho;
  ho.x = f2bf(val[0]); ho.y = f2bf(val[1]);
  ho.z = f2bf(val[2]); ho.w = f2bf(val[3]);
  *(ushort4*)(xb + (size_t)i * 4) = ho;      // bf16 row-major plane (prop input)
  const int r  = i >> 5;
  const int k0 = (i & 31) << 2;
  const size_t pi = apidx(r, k0, 4);
  *(ushort4*)(xh + pi) = ho;                 // A-pack hi (GEMM)
}

// ---------------- preprocessing ----------------

__global__ void k_decode(const void* __restrict__ ei, const int* __restrict__ eflag,
                         int E, int N, int* __restrict__ rowi, int* __restrict__ coli,
                         float* __restrict__ deg, int* __restrict__ cnt) {
  int e = blockIdx.x * blockDim.x + threadIdx.x;
  if (e >= E) return;
  int f = *eflag;
  int r, c;
  if (f) {
    const long long* q = (const long long*)ei;
    r = (int)q[e]; c = (int)q[e + E];
  } else {
    const int* q = (const int*)ei;
    r = q[e]; c = q[e + E];
  }
  r = min(max(r, 0), N - 1);
  c = min(max(c, 0), N - 1);
  rowi[e] = r; coli[e] = c;
  atomicAdd(&deg[r], 1.0f);
  atomicAdd(&cnt[c], 1);
}

// 1024-thread shuffle scan fused with dis = rsqrt(deg)
__global__ __launch_bounds__(1024) void k_scan(const int* __restrict__ cnt,
                                               int* __restrict__ colPtr,
                                               int* __restrict__ cursor,
                                               const float* __restrict__ deg,
                                               float* __restrict__ dis, int n) {
  __shared__ int ws[16];
  const int t = threadIdx.x;
  const int lane = t & 63;
  const int w = t >> 6;
  int carry = 0;
  for (int base = 0; base < n; base += 1024) {
    int i = base + t;
    int v = (i < n) ? cnt[i] : 0;
    if (i < n) {
      float d = deg[i];
      dis[i] = (d > 0.f) ? rsqrtf(d) : 0.f;
    }
    int x = v;
#pragma unroll
    for (int off = 1; off < 64; off <<= 1) {
      int y = __shfl_up(x, off);
      if (lane >= off) x += y;
    }
    if (lane == 63) ws[w] = x;
    __syncthreads();
    if (w == 0) {
      int sv = (lane < 16) ? ws[lane] : 0;
#pragma unroll
      for (int off = 1; off < 16; off <<= 1) {
        int y = __shfl_up(sv, off);
        if (lane >= off) sv += y;
      }
      if (lane < 16) ws[lane] = sv;
    }
    __syncthreads();
    int woff = (w == 0) ? 0 : ws[w - 1];
    int incl = carry + woff + x;
    if (i < n) { colPtr[i + 1] = incl; cursor[i] = incl - v; }
    int tot = ws[15];
    __syncthreads();
    carry += tot;
  }
  if (t == 0) colPtr[0] = 0;
}

// place: CSC edge list as packed int2 {srcRow, w-bits}
__global__ void k_place(const int* __restrict__ rowi, const int* __restrict__ coli,
                        const float* __restrict__ dis, int* __restrict__ cursor,
                        int2* __restrict__ edges, int E) {
  int e = blockIdx.x * blockDim.x + threadIdx.x;
  if (e >= E) return;
  int r = rowi[e], c = coli[e];
  float wv = -dis[r] * dis[c];
  int pos = atomicAdd(&cursor[c], 1);
  edges[pos] = make_int2(r, __float_as_int(wv));
}

// ---------------- propagation F=128 (quarter-wave rows, 16B/lane) ----------------
// r13: gathers at full 16B/lane width (bf16x8). Quarter-wave (16 lanes) covers
// one 256B row -> 4 edges PER GATHER INSTRUCTION (was 2 at 8B/lane).
// Per-edge wave-instructions ~2.75 (was ~7); dummy-slot gathers for deg~16
// drop from 16 to <=3 (16-edge chunks). Guarded metadata gives w=0,r=0.
__global__ __launch_bounds__(256) void k_prop128(
    const u16* __restrict__ z, const u16* __restrict__ base,
    u16* __restrict__ outB, u16* __restrict__ outH,
    const int* __restrict__ colPtr, const int2* __restrict__ edges,
    int N, float alpha, float beta) {
  const int lane = threadIdx.x & 63;
  const int c = blockIdx.x * 4 + (threadIdx.x >> 6);
  if (c >= N) return;
  const int q4 = lane >> 4;          // quarter 0..3: edge slot within step
  const int li = lane & 15;          // col group: cols 8*li..8*li+7
  const int s = colPtr[c], e = colPtr[c + 1];
  float accA[8] = {0.f, 0.f, 0.f, 0.f, 0.f, 0.f, 0.f, 0.f};
  float accB[8] = {0.f, 0.f, 0.f, 0.f, 0.f, 0.f, 0.f, 0.f};

  for (int j0 = s; j0 < e; j0 += 64) {
    const int take = min(64, e - j0);
    int rI = 0; float wI = 0.f;
    if (j0 + lane < e) {
      int2 ew = edges[j0 + lane];
      rI = ew.x; wI = __int_as_float(ew.y);
    }
    for (int pp = 0; pp < take; pp += 16) {   // 16 edges / chunk (4 steps x 4)
      int rr[4]; float ww[4];
#pragma unroll
      for (int p = 0; p < 4; p++) {
        rr[p] = __shfl(rI, pp + p * 4 + q4);
        ww[p] = __shfl(wI, pp + p * 4 + q4);
      }
      bf16x8 zz[4];
#pragma unroll
      for (int p = 0; p < 4; p++)
        zz[p] = *(const bf16x8*)(z + (size_t)rr[p] * 128 + li * 8);
#pragma unroll
      for (int p = 0; p < 4; p++) {
        const float wk = ww[p];
        float* A = (p & 1) ? accB : accA;
#pragma unroll
        for (int j = 0; j < 8; j++)
          A[j] = fmaf(wk, bf2f((u16)zz[p][j]), A[j]);
      }
    }
  }

  float a[8];
#pragma unroll
  for (int j = 0; j < 8; j++) {
    a[j] = accA[j] + accB[j];
    a[j] += __shfl_xor(a[j], 16);   // combine quarters 0<->1, 2<->3
    a[j] += __shfl_xor(a[j], 32);   // combine halves
  }

  if (lane < 16) {
    const size_t o = (size_t)c * 128 + li * 8;
    float vv[8];
#pragma unroll
    for (int j = 0; j < 8; j++) vv[j] = alpha * a[j];
    if (base != nullptr) {
      bf16x8 b = *(const bf16x8*)(base + o);
#pragma unroll
      for (int j = 0; j < 8; j++) vv[j] = fmaf(beta, bf2f((u16)b[j]), vv[j]);
    }
    bf16x8 ho;
#pragma unroll
    for (int j = 0; j < 8; j++) ho[j] = (short)f2bf(vv[j]);
    if (outB) *(bf16x8*)(outB + o) = ho;      // bf16 row-major (next prop)
    const size_t pi = apidx(c, li << 3, 4);   // A-pack hi, Fi=128 (contig 8)
    *(bf16x8*)(outH + pi) = ho;
  }
}

// ---------------- propagation F=256 (half-wave rows, 16B/lane) ----------------
__global__ __launch_bounds__(256) void k_prop256(
    const u16* __restrict__ z, const u16* __restrict__ base,
    u16* __restrict__ outB, u16* __restrict__ outH,
    const int* __restrict__ colPtr, const int2* __restrict__ edges,
    int N, float alpha, float beta) {
  const int lane = threadIdx.x & 63;
  const int c = blockIdx.x * 4 + (threadIdx.x >> 6);
  if (c >= N) return;
  const int h2 = lane >> 5;          // half 0..1: edge slot within step
  const int li = lane & 31;          // col group: cols 8*li..8*li+7
  const int s = colPtr[c], e = colPtr[c + 1];
  float accA[8] = {0.f, 0.f, 0.f, 0.f, 0.f, 0.f, 0.f, 0.f};
  float accB[8] = {0.f, 0.f, 0.f, 0.f, 0.f, 0.f, 0.f, 0.f};

  for (int j0 = s; j0 < e; j0 += 64) {
    const int take = min(64, e - j0);
    int rI = 0; float wI = 0.f;
    if (j0 + lane < e) {
      int2 ew = edges[j0 + lane];
      rI = ew.x; wI = __int_as_float(ew.y);
    }
    for (int pp = 0; pp < take; pp += 8) {    // 8 edges / chunk (4 steps x 2)
      int rr[4]; float ww[4];
#pragma unroll
      for (int p = 0; p < 4; p++) {
        rr[p] = __shfl(rI, pp + p * 2 + h2);
        ww[p] = __shfl(wI, pp + p * 2 + h2);
      }
      bf16x8 zz[4];
#pragma unroll
      for (int p = 0; p < 4; p++)
        zz[p] = *(const bf16x8*)(z + (size_t)rr[p] * 256 + li * 8);
#pragma unroll
      for (int p = 0; p < 4; p++) {
        const float wk = ww[p];
        float* A = (p & 1) ? accB : accA;
#pragma unroll
        for (int j = 0; j < 8; j++)
          A[j] = fmaf(wk, bf2f((u16)zz[p][j]), A[j]);
      }
    }
  }

  float a[8];
#pragma unroll
  for (int j = 0; j < 8; j++) {
    a[j] = accA[j] + accB[j];
    a[j] += __shfl_xor(a[j], 32);   // combine halves
  }

  if (lane < 32) {
    const size_t o = (size_t)c * 256 + li * 8;
    float vv[8];
#pragma unroll
    for (int j = 0; j < 8; j++) vv[j] = alpha * a[j];
    if (base != nullptr) {
      bf16x8 b = *(const bf16x8*)(base + o);
#pragma unroll
      for (int j = 0; j < 8; j++) vv[j] = fmaf(beta, bf2f((u16)b[j]), vv[j]);
    }
    bf16x8 ho;
#pragma unroll
    for (int j = 0; j < 8; j++) ho[j] = (short)f2bf(vv[j]);
    if (outB) *(bf16x8*)(outB + o) = ho;
    const size_t pi = apidx(c, li << 3, 8);   // A-pack hi, Fi=256 (contig 8)
    *(bf16x8*)(outH + pi) = ho;
  }
}

// ---------------- MFMA GEMM (LDS-free, barrier-free, XCD swizzle) ----------------
// A-lo correction optional (a0l==nullptr -> skip). r13: heads also hi-only
// (heads-lo contributes ~4e-4 RMS, an order below r12's layer noise).
// wflag (fp32 weights) keeps the B-lo correction.
// C/D mapping (verified): col = lane&31, row = (reg&3)+8*(reg>>2)+4*(lane>>5).
__global__ __launch_bounds__(256, 4) void k_gemm_mfma(
    const u16* __restrict__ a0h, const u16* __restrict__ a0l,
    const u16* __restrict__ a1h, const u16* __restrict__ a1l,
    const u16* __restrict__ a2h, const u16* __restrict__ a2l,
    const u16* __restrict__ packHi, const u16* __restrict__ packLo,
    const void* __restrict__ bias, const void* __restrict__ bias2,
    const int* __restrict__ wflagp,
    int N, int Fi, int NQ, int Fo,
    u16* __restrict__ outB, u16* __restrict__ outH, u16* __restrict__ outL,
    u16* __restrict__ outB16, float* __restrict__ outB32, int relu, int headSplit) {
  const int wflag = *wflagp;
  const bool useLo = (a0l != nullptr);
  const int tid  = threadIdx.x;
  const int lane = tid & 63;
  const int w    = tid >> 6;
  const int wm   = w >> 1;
  const int wn   = w & 1;

  const int gx = gridDim.x;
  int wg = blockIdx.x + gx * blockIdx.y;
  {
    const int nwg = gx * gridDim.y;
    const int q = nwg >> 3, r = nwg & 7;
    const int xcd = wg & 7;
    const int idx = wg >> 3;
    wg = (xcd < r ? xcd * (q + 1) : r * (q + 1) + (xcd - r) * q) + idx;
  }
  const int nt = wg % gx;
  const int mt = wg / gx;
  const int n0 = nt << 6;
  const int m0 = mt << 6;
  const int KSQ   = Fi >> 5;
  const int qsh   = __builtin_ctz(KSQ);
  const int qmask = KSQ - 1;
  const int KS    = NQ << qsh;

  const int laneoff = lane << 3;

  f32x16 acc = {};

#pragma unroll 2
  for (int ks = 0; ks < KS; ks++) {
    const int q   = ks >> qsh;
    const int ksl = ks & qmask;
    const u16* Ah = (q == 0) ? a0h : (q == 1 ? a1h : a2h);
    const size_t abase = ((size_t)(mt * KSQ + ksl) << 2) * 512 + (size_t)((wm << 1) * 512) + laneoff;
    const bf16x8 aH0 = *(const bf16x8*)(Ah + abase);
    const bf16x8 aH1 = *(const bf16x8*)(Ah + abase + 512);
    const size_t bbase = (((size_t)(nt * KS + ks) << 2) + (wn << 1)) * 512 + laneoff;
    const bf16x8 b0 = *(const bf16x8*)(packHi + bbase);
    const bf16x8 b1 = *(const bf16x8*)(packHi + bbase + 512);

    acc = __builtin_amdgcn_mfma_f32_32x32x16_bf16(aH0, b0, acc, 0, 0, 0);
    acc = __builtin_amdgcn_mfma_f32_32x32x16_bf16(aH1, b1, acc, 0, 0, 0);
    if (useLo) {
      const u16* Al = (q == 0) ? a0l : (q == 1 ? a1l : a2l);
      const bf16x8 aL0 = *(const bf16x8*)(Al + abase);
      const bf16x8 aL1 = *(const bf16x8*)(Al + abase + 512);
      acc = __builtin_amdgcn_mfma_f32_32x32x16_bf16(aL0, b0, acc, 0, 0, 0);
      acc = __builtin_amdgcn_mfma_f32_32x32x16_bf16(aL1, b1, acc, 0, 0, 0);
    }
    if (wflag) {
      const bf16x8 c0 = *(const bf16x8*)(packLo + bbase);
      const bf16x8 c1 = *(const bf16x8*)(packLo + bbase + 512);
      acc = __builtin_amdgcn_mfma_f32_32x32x16_bf16(aH0, c0, acc, 0, 0, 0);
      acc = __builtin_amdgcn_mfma_f32_32x32x16_bf16(aH1, c1, acc, 0, 0, 0);
    }
  }

  {
    const int ncol = n0 + (wn << 5) + (lane & 31);
    const int KSQo = Fo >> 5;
    int col = ncol;
    const void* bp = bias;
    size_t obase = 0;
    int FoOut = Fo;
    if (headSplit) {
      FoOut = 256;
      if (ncol >= 256) { col = ncol - 256; bp = bias2; obase = (size_t)N * 256; }
    }
    const float bv = wflag ? ((const float*)bp)[col]
                           : bf2f(((const u16*)bp)[col]);
#pragma unroll
    for (int r = 0; r < 16; r++) {
      const int m = m0 + (wm << 5) + (r & 3) + ((r >> 2) << 3) + ((lane >> 5) << 2);
      if (m < N) {
        float vv = acc[r] + bv;
        if (relu) vv = fmaxf(vv, 0.f);
        if (outH) {
          u16 h = f2bf(vv);
          const size_t pi = apidx(m, ncol, KSQo);
          outH[pi] = h;
          if (outL) outL[pi] = f2bf(vv - bf2f(h));
          if (outB) outB[(size_t)m * Fo + ncol] = h; // row-major for props
        }
        if (outB16) {
          const size_t o = obase + (size_t)m * FoOut + col;
          if (wflag) outB32[o] = vv;
          else       outB16[o] = f2bf(vv);
        }
      }
    }
  }
}

// ---------------- host (kernel launches ONLY) ----------------

static size_t align256(size_t x) { return (x + 255) & ~(size_t)255; }

extern "C" void kernel_launch(void* const* d_in, const int* in_sizes, int n_in,
                              void* d_out, int out_size, void* d_ws, size_t ws_size,
                              hipStream_t stream) {
  const void* v    = d_in[0];
  const void* ei   = d_in[1];
  const void* W1   = d_in[2];
  const void* b1   = d_in[3];
  const void* W2   = d_in[4];
  const void* b2   = d_in[5];
  const void* W3   = d_in[6];
  const void* b3   = d_in[7];
  const void* Wmu  = d_in[8];
  const void* bmu  = d_in[9];
  const void* Wstd = d_in[10];
  const void* bstd = d_in[11];
  (void)n_in; (void)ws_size;

  const int N = in_sizes[0] / 128;   // 10000
  const int E = in_sizes[1] / 2;     // 160000
  const size_t NP = ((size_t)N + 63) & ~(size_t)63;

  char* base = (char*)d_ws;
  size_t off = 0;
  auto carve = [&](size_t bytes) { void* p = base + off; off = align256(off + bytes); return p; };

  int*   eflag  = (int*)  carve(4);      // flags[0]=eflag, flags[1]=vflag
  int*   vflag  = (int*)  carve(4);
  int*   rowi   = (int*)  carve((size_t)E * 4);
  int*   coli   = (int*)  carve((size_t)E * 4);
  float* deg    = (float*)carve((size_t)N * 4);
  float* dis    = (float*)carve((size_t)N * 4);
  int*   cnt    = (int*)  carve((size_t)N * 4);
  int*   colPtr = (int*)  carve((size_t)(N + 1) * 4);
  int*   cursor = (int*)  carve((size_t)N * 4);
  int2*  edges  = (int2*) carve((size_t)E * 8);

  u16* pW1h = (u16*)carve((size_t)384 * 128 * 2);
  u16* pW1l = (u16*)carve((size_t)384 * 128 * 2);
  u16* pW2h = (u16*)carve((size_t)384 * 256 * 2);
  u16* pW2l = (u16*)carve((size_t)384 * 256 * 2);
  u16* pW3h = (u16*)carve((size_t)768 * 512 * 2);
  u16* pW3l = (u16*)carve((size_t)768 * 512 * 2);
  u16* pHh  = (u16*)carve((size_t)2 * 512 * 256 * 2);
  u16* pHl  = (u16*)carve((size_t)2 * 512 * 256 * 2);

  // activation storage: bf16 row-major planes (prop gathers) + hi packs (GEMM)
  u16* Xb  = (u16*)carve(NP * 256 * 2);
  u16* Xh  = (u16*)carve(NP * 256 * 2);
  u16* Yb  = (u16*)carve(NP * 128 * 2);
  u16* Yh  = (u16*)carve(NP * 512 * 2);
  u16* t1b = (u16*)carve(NP * 256 * 2);
  u16* t1h = (u16*)carve(NP * 256 * 2);
  u16* t2h = (u16*)carve(NP * 256 * 2);

  // 1) fused probes + zero + sentinel
  const int zb = (N + 255) / 256;
  const int sb = (out_size + 255) / 256;
  k_init<<<2 + zb + sb, 256, 0, stream>>>((const unsigned*)v, 1024, vflag,
                                          (const unsigned*)ei, 2048, eflag,
                                          deg, cnt, N, zb, (u16*)d_out, out_size);

  // 2) fused weight packs + input convert
  const int n4 = N * 128 / 4;
  const int c1 = 24, c2 = c1 + 48, c3 = c2 + 192, c4 = c3 + 64, c5 = c4 + 64;
  const int cTot = c5 + (n4 + 255) / 256;
  k_pack<<<cTot, 256, 0, stream>>>(W1, W2, W3, Wmu, Wstd,
                                   pW1h, pW1l, pW2h, pW2l, pW3h, pW3l, pHh, pHl,
                                   v, Xb, Xh, n4, eflag,
                                   c1, c2, c3, c4, c5);

  // 3) graph preprocessing
  k_decode<<<(E + 255) / 256, 256, 0, stream>>>(ei, eflag, E, N, rowi, coli, deg, cnt);
  k_scan<<<1, 1024, 0, stream>>>(cnt, colPtr, cursor, deg, dis, N);
  k_place<<<(E + 255) / 256, 256, 0, stream>>>(rowi, coli, dis, cursor, edges, E);

  const int gM = (N + 63) / 64;
  const int gP = (N + 3) / 4;

  // layer 1: Fi=128 -> Fo=128, X -> Y (hi-only GEMM)
  k_prop128<<<gP, 256, 0, stream>>>(Xb, nullptr, t1b, t1h, colPtr, edges, N, 1.f, 0.f);
  k_prop128<<<gP, 256, 0, stream>>>(t1b, Xb, nullptr, t2h, colPtr, edges, N, 2.f, -1.f);
  k_gemm_mfma<<<dim3(2, gM), 256, 0, stream>>>(Xh, nullptr, t1h, nullptr, t2h, nullptr,
                                               pW1h, pW1l, b1, b1, vflag, N, 128, 3, 128,
                                               Yb, Yh, nullptr, nullptr, nullptr, 1, 0);

  // layer 2: Fi=128 -> Fo=256, Y -> X (hi-only GEMM)
  k_prop128<<<gP, 256, 0, stream>>>(Yb, nullptr, t1b, t1h, colPtr, edges, N, 1.f, 0.f);
  k_prop128<<<gP, 256, 0, stream>>>(t1b, Yb, nullptr, t2h, colPtr, edges, N, 2.f, -1.f);
  k_gemm_mfma<<<dim3(4, gM), 256, 0, stream>>>(Yh, nullptr, t1h, nullptr, t2h, nullptr,
                                               pW2h, pW2l, b2, b2, vflag, N, 128, 3, 256,
                                               Xb, Xh, nullptr, nullptr, nullptr, 1, 0);

  // layer 3: Fi=256 -> Fo=512, X -> Y (hi-only GEMM; hi pack only)
  k_prop256<<<gP, 256, 0, stream>>>(Xb, nullptr, t1b, t1h, colPtr, edges, N, 1.f, 0.f);
  k_prop256<<<gP, 256, 0, stream>>>(t1b, Xb, nullptr, t2h, colPtr, edges, N, 2.f, -1.f);
  k_gemm_mfma<<<dim3(8, gM), 256, 0, stream>>>(Xh, nullptr, t1h, nullptr, t2h, nullptr,
                                               pW3h, pW3l, b3, b3, vflag, N, 256, 3, 512,
                                               nullptr, Yh, nullptr, nullptr, nullptr, 1, 0);

  // fused heads: hi-only x3 operand (r13; pre-commit: revert if absmax fails)
  k_gemm_mfma<<<dim3(8, gM), 256, 0, stream>>>(Yh, nullptr, nullptr, nullptr, nullptr, nullptr,
                                               pHh, pHl, bmu, bstd, vflag, N, 512, 1, 512,
                                               nullptr, nullptr, nullptr,
                                               (u16*)d_out, (float*)d_out, 0, 1);
}

// Round 14
// 270.356 us; speedup vs baseline: 1.2801x; 1.0066x over previous
//
#include <hip/hip_runtime.h>
#include <hip/hip_bf16.h>

// ---------------- types & helpers ----------------

typedef __attribute__((ext_vector_type(8)))  short bf16x8;   // 8 bf16 = 4 VGPR
typedef __attribute__((ext_vector_type(16))) float f32x16;   // MFMA 32x32 acc
typedef unsigned short u16;

__device__ __forceinline__ u16 f2bf(float x) {               // RNE fp32->bf16
  union { float f; unsigned u; } c; c.f = x;
  return (u16)((c.u + 0x7fffu + ((c.u >> 16) & 1u)) >> 16);
}
__device__ __forceinline__ float bf2f(u16 u) {               // exact bf16->fp32
  union { unsigned u; float f; } c; c.u = ((unsigned)u) << 16;
  return c.f;
}

// A-pack addressing (fragment-linear, 64-row m-tiles, 32-k ksteps).
// Element (row r, col k), KSQ = Fi/32:
//   slot = ((r>>6)*KSQ + (k>>5))*4 + ((r>>5)&1)*2 + ((k>>4)&1)
//   lane = (r&31) + ((k>>3)&1)*32 ;  j = k&7 ;  idx = slot*512 + lane*8 + j
__device__ __forceinline__ size_t apidx(int r, int k, int KSQ) {
  const int slot = (((r >> 6) * KSQ + (k >> 5)) << 2) + (((r >> 5) & 1) << 1) + ((k >> 4) & 1);
  return ((size_t)slot << 9) + (size_t)(((((k >> 3) & 1) << 5) | (r & 31)) << 3) + (k & 7);
}

// ---------------- k0: dtype probes + zero + sentinel ----------------
__global__ void k_init(const unsigned* __restrict__ v, int nv, int* __restrict__ vflag,
                       const unsigned* __restrict__ ei, int ne, int* __restrict__ eflag,
                       float* __restrict__ deg, int* __restrict__ cnt, int n, int zb,
                       u16* __restrict__ outSent, int outN) {
  __shared__ unsigned red[256];
  if (blockIdx.x == 0) {
    int ok = 0;
    for (int i = threadIdx.x; i < nv; i += 256) {
      unsigned lo = v[i] & 0xffffu;
      unsigned ef = (lo >> 7) & 0xffu;
      if (ef >= 115u && ef <= 140u) ok++;
    }
    red[threadIdx.x] = (unsigned)ok;
    __syncthreads();
    for (int s = 128; s > 0; s >>= 1) {
      if (threadIdx.x < s) red[threadIdx.x] += red[threadIdx.x + s];
      __syncthreads();
    }
    if (threadIdx.x == 0) *vflag = ((int)red[0] < nv / 2) ? 1 : 0;
  } else if (blockIdx.x == 1) {
    unsigned acc = 0;
    for (int i = threadIdx.x; i < ne; i += 256)
      if (i & 1) acc |= ei[i];
    red[threadIdx.x] = acc;
    __syncthreads();
    for (int s = 128; s > 0; s >>= 1) {
      if (threadIdx.x < s) red[threadIdx.x] |= red[threadIdx.x + s];
      __syncthreads();
    }
    if (threadIdx.x == 0) *eflag = (red[0] == 0u) ? 1 : 0;
  } else if (blockIdx.x < 2 + zb) {
    int i = (blockIdx.x - 2) * 256 + threadIdx.x;
    if (i < n) { deg[i] = 0.0f; cnt[i] = 0; }
  } else {
    int i = (blockIdx.x - 2 - zb) * 256 + threadIdx.x;
    if (i < outN) outSent[i] = 0x3F00;
  }
}

// ---------------- k1: fused {5 weight packs + input convert + edge decode} ----------------
// pack & decode are independent; both need only k0's outputs (flags, zeroed
// deg/cnt). Fusing removes one dispatch and co-schedules the two memory-bound
// phases across CUs. (r14 also fixes the latent flags[1] bug: vflag is passed
// as an explicit pointer, not an offset into poisoned workspace.)
__device__ __forceinline__ void wpack_dev(
    const void* __restrict__ W, int wflag, int K, int Fo,
    u16* __restrict__ dstHi, u16* __restrict__ dstLo, int blk, int tid) {
  const int t = blk * 256 + tid;
  const int KS = K >> 5;
  const int total = (Fo >> 6) * KS * 4;
  const int s = t >> 6;
  if (s >= total) return;
  const int lane = t & 63;
  const int fb = s & 3;
  const int sk = s >> 2;
  const int ks = sk % KS;
  const int nt = sk / KS;
  const int col = (nt << 6) + ((fb >> 1) << 5) + (lane & 31);
  const int row = (ks << 5) + ((fb & 1) << 4) + ((lane >> 5) << 3);
  bf16x8 hi;
  if (wflag) {
    const float* Wf = (const float*)W;
    bf16x8 lo;
#pragma unroll
    for (int j = 0; j < 8; j++) {
      float wv = Wf[(size_t)(row + j) * Fo + col];
      u16 h = f2bf(wv);
      hi[j] = (short)h;
      lo[j] = (short)f2bf(wv - bf2f(h));
    }
    *(bf16x8*)(dstLo + (size_t)s * 512 + lane * 8) = lo;
  } else {
    const u16* Wb = (const u16*)W;
#pragma unroll
    for (int j = 0; j < 8; j++)
      hi[j] = (short)Wb[(size_t)(row + j) * Fo + col];
  }
  *(bf16x8*)(dstHi + (size_t)s * 512 + lane * 8) = hi;
}

__global__ void k_pack(const void* __restrict__ W1, const void* __restrict__ W2,
                       const void* __restrict__ W3, const void* __restrict__ Wmu,
                       const void* __restrict__ Wstd,
                       u16* pW1h, u16* pW1l, u16* pW2h, u16* pW2l,
                       u16* pW3h, u16* pW3l, u16* pHh, u16* pHl,
                       const void* __restrict__ v, u16* __restrict__ xb,
                       u16* __restrict__ xh, int n4,
                       const int* __restrict__ vflagp, const int* __restrict__ eflagp,
                       const void* __restrict__ ei, int E, int N,
                       int* __restrict__ rowi, int* __restrict__ coli,
                       float* __restrict__ deg, int* __restrict__ cnt,
                       int c1, int c2, int c3, int c4, int c5, int c6) {
  const int b = blockIdx.x;
  const int tid = threadIdx.x;
  if (b < c5) {
    const int wflag = *vflagp;   // weights share input dtype
    if (b < c1)      { wpack_dev(W1,   wflag, 384, 128, pW1h, pW1l, b,      tid); return; }
    if (b < c2)      { wpack_dev(W2,   wflag, 384, 256, pW2h, pW2l, b - c1, tid); return; }
    if (b < c3)      { wpack_dev(W3,   wflag, 768, 512, pW3h, pW3l, b - c2, tid); return; }
    if (b < c4)      { wpack_dev(Wmu,  wflag, 512, 256, pHh,          pHl,          b - c3, tid); return; }
    wpack_dev(Wstd, wflag, 512, 256, pHh + 131072, pHl + 131072, b - c4, tid);
    return;
  }
  if (b < c6) {
    // input convert: v (bf16/fp32) -> bf16 row-major plane + A-pack hi (Fi=128)
    const int wflag = *vflagp;
    const int i = (b - c5) * 256 + tid;
    if (i >= n4) return;
    float val[4];
    if (wflag) {
      float4 t = ((const float4*)v)[i];
      val[0] = t.x; val[1] = t.y; val[2] = t.z; val[3] = t.w;
    } else {
      ushort4 t = ((const ushort4*)v)[i];
      val[0] = bf2f(t.x); val[1] = bf2f(t.y); val[2] = bf2f(t.z); val[3] = bf2f(t.w);
    }
    ushort4 ho;
    ho.x = f2bf(val[0]); ho.y = f2bf(val[1]);
    ho.z = f2bf(val[2]); ho.w = f2bf(val[3]);
    *(ushort4*)(xb + (size_t)i * 4) = ho;
    const int r  = i >> 5;
    const int k0 = (i & 31) << 2;
    const size_t pi = apidx(r, k0, 4);
    *(ushort4*)(xh + pi) = ho;
    return;
  }
  // edge decode (needs zeroed deg/cnt from k0)
  const int e = (b - c6) * 256 + tid;
  if (e >= E) return;
  const int f = *eflagp;
  int r, c;
  if (f) {
    const long long* q = (const long long*)ei;
    r = (int)q[e]; c = (int)q[e + E];
  } else {
    const int* q = (const int*)ei;
    r = q[e]; c = q[e + E];
  }
  r = min(max(r, 0), N - 1);
  c = min(max(c, 0), N - 1);
  rowi[e] = r; coli[e] = c;
  atomicAdd(&deg[r], 1.0f);
  atomicAdd(&cnt[c], 1);
}

// ---------------- preprocessing ----------------

// 1024-thread shuffle scan fused with dis = rsqrt(deg)
__global__ __launch_bounds__(1024) void k_scan(const int* __restrict__ cnt,
                                               int* __restrict__ colPtr,
                                               int* __restrict__ cursor,
                                               const float* __restrict__ deg,
                                               float* __restrict__ dis, int n) {
  __shared__ int ws[16];
  const int t = threadIdx.x;
  const int lane = t & 63;
  const int w = t >> 6;
  int carry = 0;
  for (int base = 0; base < n; base += 1024) {
    int i = base + t;
    int v = (i < n) ? cnt[i] : 0;
    if (i < n) {
      float d = deg[i];
      dis[i] = (d > 0.f) ? rsqrtf(d) : 0.f;
    }
    int x = v;
#pragma unroll
    for (int off = 1; off < 64; off <<= 1) {
      int y = __shfl_up(x, off);
      if (lane >= off) x += y;
    }
    if (lane == 63) ws[w] = x;
    __syncthreads();
    if (w == 0) {
      int sv = (lane < 16) ? ws[lane] : 0;
#pragma unroll
      for (int off = 1; off < 16; off <<= 1) {
        int y = __shfl_up(sv, off);
        if (lane >= off) sv += y;
      }
      if (lane < 16) ws[lane] = sv;
    }
    __syncthreads();
    int woff = (w == 0) ? 0 : ws[w - 1];
    int incl = carry + woff + x;
    if (i < n) { colPtr[i + 1] = incl; cursor[i] = incl - v; }
    int tot = ws[15];
    __syncthreads();
    carry += tot;
  }
  if (t == 0) colPtr[0] = 0;
}

// place: CSC edge list as packed int2 {srcRow, w-bits}
__global__ void k_place(const int* __restrict__ rowi, const int* __restrict__ coli,
                        const float* __restrict__ dis, int* __restrict__ cursor,
                        int2* __restrict__ edges, int E) {
  int e = blockIdx.x * blockDim.x + threadIdx.x;
  if (e >= E) return;
  int r = rowi[e], c = coli[e];
  float wv = -dis[r] * dis[c];
  int pos = atomicAdd(&cursor[c], 1);
  edges[pos] = make_int2(r, __float_as_int(wv));
}

// ---------------- propagation F=128 (quarter-wave rows, 16B/lane) ----------------
// Gathers at 16B/lane width; quarter-wave (16 lanes) covers one 256B row ->
// 4 edges per gather instruction. Guarded metadata gives w=0,r=0.
__global__ __launch_bounds__(256) void k_prop128(
    const u16* __restrict__ z, const u16* __restrict__ base,
    u16* __restrict__ outB, u16* __restrict__ outH,
    const int* __restrict__ colPtr, const int2* __restrict__ edges,
    int N, float alpha, float beta) {
  const int lane = threadIdx.x & 63;
  const int c = blockIdx.x * 4 + (threadIdx.x >> 6);
  if (c >= N) return;
  const int q4 = lane >> 4;
  const int li = lane & 15;
  const int s = colPtr[c], e = colPtr[c + 1];
  float accA[8] = {0.f, 0.f, 0.f, 0.f, 0.f, 0.f, 0.f, 0.f};
  float accB[8] = {0.f, 0.f, 0.f, 0.f, 0.f, 0.f, 0.f, 0.f};

  for (int j0 = s; j0 < e; j0 += 64) {
    const int take = min(64, e - j0);
    int rI = 0; float wI = 0.f;
    if (j0 + lane < e) {
      int2 ew = edges[j0 + lane];
      rI = ew.x; wI = __int_as_float(ew.y);
    }
    for (int pp = 0; pp < take; pp += 16) {
      int rr[4]; float ww[4];
#pragma unroll
      for (int p = 0; p < 4; p++) {
        rr[p] = __shfl(rI, pp + p * 4 + q4);
        ww[p] = __shfl(wI, pp + p * 4 + q4);
      }
      bf16x8 zz[4];
#pragma unroll
      for (int p = 0; p < 4; p++)
        zz[p] = *(const bf16x8*)(z + (size_t)rr[p] * 128 + li * 8);
#pragma unroll
      for (int p = 0; p < 4; p++) {
        const float wk = ww[p];
        float* A = (p & 1) ? accB : accA;
#pragma unroll
        for (int j = 0; j < 8; j++)
          A[j] = fmaf(wk, bf2f((u16)zz[p][j]), A[j]);
      }
    }
  }

  float a[8];
#pragma unroll
  for (int j = 0; j < 8; j++) {
    a[j] = accA[j] + accB[j];
    a[j] += __shfl_xor(a[j], 16);
    a[j] += __shfl_xor(a[j], 32);
  }

  if (lane < 16) {
    const size_t o = (size_t)c * 128 + li * 8;
    float vv[8];
#pragma unroll
    for (int j = 0; j < 8; j++) vv[j] = alpha * a[j];
    if (base != nullptr) {
      bf16x8 b = *(const bf16x8*)(base + o);
#pragma unroll
      for (int j = 0; j < 8; j++) vv[j] = fmaf(beta, bf2f((u16)b[j]), vv[j]);
    }
    bf16x8 ho;
#pragma unroll
    for (int j = 0; j < 8; j++) ho[j] = (short)f2bf(vv[j]);
    if (outB) *(bf16x8*)(outB + o) = ho;
    const size_t pi = apidx(c, li << 3, 4);
    *(bf16x8*)(outH + pi) = ho;
  }
}

// ---------------- propagation F=256 (half-wave rows, 16B/lane) ----------------
__global__ __launch_bounds__(256) void k_prop256(
    const u16* __restrict__ z, const u16* __restrict__ base,
    u16* __restrict__ outB, u16* __restrict__ outH,
    const int* __restrict__ colPtr, const int2* __restrict__ edges,
    int N, float alpha, float beta) {
  const int lane = threadIdx.x & 63;
  const int c = blockIdx.x * 4 + (threadIdx.x >> 6);
  if (c >= N) return;
  const int h2 = lane >> 5;
  const int li = lane & 31;
  const int s = colPtr[c], e = colPtr[c + 1];
  float accA[8] = {0.f, 0.f, 0.f, 0.f, 0.f, 0.f, 0.f, 0.f};
  float accB[8] = {0.f, 0.f, 0.f, 0.f, 0.f, 0.f, 0.f, 0.f};

  for (int j0 = s; j0 < e; j0 += 64) {
    const int take = min(64, e - j0);
    int rI = 0; float wI = 0.f;
    if (j0 + lane < e) {
      int2 ew = edges[j0 + lane];
      rI = ew.x; wI = __int_as_float(ew.y);
    }
    for (int pp = 0; pp < take; pp += 8) {
      int rr[4]; float ww[4];
#pragma unroll
      for (int p = 0; p < 4; p++) {
        rr[p] = __shfl(rI, pp + p * 2 + h2);
        ww[p] = __shfl(wI, pp + p * 2 + h2);
      }
      bf16x8 zz[4];
#pragma unroll
      for (int p = 0; p < 4; p++)
        zz[p] = *(const bf16x8*)(z + (size_t)rr[p] * 256 + li * 8);
#pragma unroll
      for (int p = 0; p < 4; p++) {
        const float wk = ww[p];
        float* A = (p & 1) ? accB : accA;
#pragma unroll
        for (int j = 0; j < 8; j++)
          A[j] = fmaf(wk, bf2f((u16)zz[p][j]), A[j]);
      }
    }
  }

  float a[8];
#pragma unroll
  for (int j = 0; j < 8; j++) {
    a[j] = accA[j] + accB[j];
    a[j] += __shfl_xor(a[j], 32);
  }

  if (lane < 32) {
    const size_t o = (size_t)c * 256 + li * 8;
    float vv[8];
#pragma unroll
    for (int j = 0; j < 8; j++) vv[j] = alpha * a[j];
    if (base != nullptr) {
      bf16x8 b = *(const bf16x8*)(base + o);
#pragma unroll
      for (int j = 0; j < 8; j++) vv[j] = fmaf(beta, bf2f((u16)b[j]), vv[j]);
    }
    bf16x8 ho;
#pragma unroll
    for (int j = 0; j < 8; j++) ho[j] = (short)f2bf(vv[j]);
    if (outB) *(bf16x8*)(outB + o) = ho;
    const size_t pi = apidx(c, li << 3, 8);
    *(bf16x8*)(outH + pi) = ho;
  }
}

// ---------------- MFMA GEMM (LDS-free, barrier-free, XCD swizzle; FROZEN) ----------------
// hi-only A everywhere (r12/r13 verified: absmax 0.0078, passing).
// wflag (fp32 weights) keeps the B-lo correction.
// C/D mapping (verified): col = lane&31, row = (reg&3)+8*(reg>>2)+4*(lane>>5).
__global__ __launch_bounds__(256, 4) void k_gemm_mfma(
    const u16* __restrict__ a0h, const u16* __restrict__ a1h,
    const u16* __restrict__ a2h,
    const u16* __restrict__ packHi, const u16* __restrict__ packLo,
    const void* __restrict__ bias, const void* __restrict__ bias2,
    const int* __restrict__ wflagp,
    int N, int Fi, int NQ, int Fo,
    u16* __restrict__ outB, u16* __restrict__ outH,
    u16* __restrict__ outB16, float* __restrict__ outB32, int relu, int headSplit) {
  const int wflag = *wflagp;
  const int tid  = threadIdx.x;
  const int lane = tid & 63;
  const int w    = tid >> 6;
  const int wm   = w >> 1;
  const int wn   = w & 1;

  const int gx = gridDim.x;
  int wg = blockIdx.x + gx * blockIdx.y;
  {
    const int nwg = gx * gridDim.y;
    const int q = nwg >> 3, r = nwg & 7;
    const int xcd = wg & 7;
    const int idx = wg >> 3;
    wg = (xcd < r ? xcd * (q + 1) : r * (q + 1) + (xcd - r) * q) + idx;
  }
  const int nt = wg % gx;
  const int mt = wg / gx;
  const int n0 = nt << 6;
  const int m0 = mt << 6;
  const int KSQ   = Fi >> 5;
  const int qsh   = __builtin_ctz(KSQ);
  const int qmask = KSQ - 1;
  const int KS    = NQ << qsh;

  const int laneoff = lane << 3;

  f32x16 acc = {};

#pragma unroll 2
  for (int ks = 0; ks < KS; ks++) {
    const int q   = ks >> qsh;
    const int ksl = ks & qmask;
    const u16* Ah = (q == 0) ? a0h : (q == 1 ? a1h : a2h);
    const size_t abase = ((size_t)(mt * KSQ + ksl) << 2) * 512 + (size_t)((wm << 1) * 512) + laneoff;
    const bf16x8 aH0 = *(const bf16x8*)(Ah + abase);
    const bf16x8 aH1 = *(const bf16x8*)(Ah + abase + 512);
    const size_t bbase = (((size_t)(nt * KS + ks) << 2) + (wn << 1)) * 512 + laneoff;
    const bf16x8 b0 = *(const bf16x8*)(packHi + bbase);
    const bf16x8 b1 = *(const bf16x8*)(packHi + bbase + 512);

    acc = __builtin_amdgcn_mfma_f32_32x32x16_bf16(aH0, b0, acc, 0, 0, 0);
    acc = __builtin_amdgcn_mfma_f32_32x32x16_bf16(aH1, b1, acc, 0, 0, 0);
    if (wflag) {
      const bf16x8 c0 = *(const bf16x8*)(packLo + bbase);
      const bf16x8 c1 = *(const bf16x8*)(packLo + bbase + 512);
      acc = __builtin_amdgcn_mfma_f32_32x32x16_bf16(aH0, c0, acc, 0, 0, 0);
      acc = __builtin_amdgcn_mfma_f32_32x32x16_bf16(aH1, c1, acc, 0, 0, 0);
    }
  }

  {
    const int ncol = n0 + (wn << 5) + (lane & 31);
    const int KSQo = Fo >> 5;
    int col = ncol;
    const void* bp = bias;
    size_t obase = 0;
    int FoOut = Fo;
    if (headSplit) {
      FoOut = 256;
      if (ncol >= 256) { col = ncol - 256; bp = bias2; obase = (size_t)N * 256; }
    }
    const float bv = wflag ? ((const float*)bp)[col]
                           : bf2f(((const u16*)bp)[col]);
#pragma unroll
    for (int r = 0; r < 16; r++) {
      const int m = m0 + (wm << 5) + (r & 3) + ((r >> 2) << 3) + ((lane >> 5) << 2);
      if (m < N) {
        float vv = acc[r] + bv;
        if (relu) vv = fmaxf(vv, 0.f);
        if (outH) {
          u16 h = f2bf(vv);
          outH[apidx(m, ncol, KSQo)] = h;
          if (outB) outB[(size_t)m * Fo + ncol] = h;
        }
        if (outB16) {
          const size_t o = obase + (size_t)m * FoOut + col;
          if (wflag) outB32[o] = vv;
          else       outB16[o] = f2bf(vv);
        }
      }
    }
  }
}

// ---------------- host (kernel launches ONLY) ----------------

static size_t align256(size_t x) { return (x + 255) & ~(size_t)255; }

extern "C" void kernel_launch(void* const* d_in, const int* in_sizes, int n_in,
                              void* d_out, int out_size, void* d_ws, size_t ws_size,
                              hipStream_t stream) {
  const void* v    = d_in[0];
  const void* ei   = d_in[1];
  const void* W1   = d_in[2];
  const void* b1   = d_in[3];
  const void* W2   = d_in[4];
  const void* b2   = d_in[5];
  const void* W3   = d_in[6];
  const void* b3   = d_in[7];
  const void* Wmu  = d_in[8];
  const void* bmu  = d_in[9];
  const void* Wstd = d_in[10];
  const void* bstd = d_in[11];
  (void)n_in; (void)ws_size;

  const int N = in_sizes[0] / 128;   // 10000
  const int E = in_sizes[1] / 2;     // 160000
  const size_t NP = ((size_t)N + 63) & ~(size_t)63;

  char* base = (char*)d_ws;
  size_t off = 0;
  auto carve = [&](size_t bytes) { void* p = base + off; off = align256(off + bytes); return p; };

  int*   eflag  = (int*)  carve(4);
  int*   vflag  = (int*)  carve(4);
  int*   rowi   = (int*)  carve((size_t)E * 4);
  int*   coli   = (int*)  carve((size_t)E * 4);
  float* deg    = (float*)carve((size_t)N * 4);
  float* dis    = (float*)carve((size_t)N * 4);
  int*   cnt    = (int*)  carve((size_t)N * 4);
  int*   colPtr = (int*)  carve((size_t)(N + 1) * 4);
  int*   cursor = (int*)  carve((size_t)N * 4);
  int2*  edges  = (int2*) carve((size_t)E * 8);

  u16* pW1h = (u16*)carve((size_t)384 * 128 * 2);
  u16* pW1l = (u16*)carve((size_t)384 * 128 * 2);
  u16* pW2h = (u16*)carve((size_t)384 * 256 * 2);
  u16* pW2l = (u16*)carve((size_t)384 * 256 * 2);
  u16* pW3h = (u16*)carve((size_t)768 * 512 * 2);
  u16* pW3l = (u16*)carve((size_t)768 * 512 * 2);
  u16* pHh  = (u16*)carve((size_t)2 * 512 * 256 * 2);
  u16* pHl  = (u16*)carve((size_t)2 * 512 * 256 * 2);

  // activation storage: bf16 row-major planes (prop gathers) + hi packs (GEMM)
  u16* Xb  = (u16*)carve(NP * 256 * 2);
  u16* Xh  = (u16*)carve(NP * 256 * 2);
  u16* Yb  = (u16*)carve(NP * 128 * 2);
  u16* Yh  = (u16*)carve(NP * 512 * 2);
  u16* t1b = (u16*)carve(NP * 256 * 2);
  u16* t1h = (u16*)carve(NP * 256 * 2);
  u16* t2h = (u16*)carve(NP * 256 * 2);

  // k0: probes + zero + sentinel
  const int zb = (N + 255) / 256;
  const int sb = (out_size + 255) / 256;
  k_init<<<2 + zb + sb, 256, 0, stream>>>((const unsigned*)v, 1024, vflag,
                                          (const unsigned*)ei, 2048, eflag,
                                          deg, cnt, N, zb, (u16*)d_out, out_size);

  // k1: fused weight packs + input convert + edge decode
  const int n4 = N * 128 / 4;
  const int c1 = 24, c2 = c1 + 48, c3 = c2 + 192, c4 = c3 + 64, c5 = c4 + 64;
  const int c6 = c5 + (n4 + 255) / 256;
  const int db = (E + 255) / 256;
  k_pack<<<c6 + db, 256, 0, stream>>>(W1, W2, W3, Wmu, Wstd,
                                      pW1h, pW1l, pW2h, pW2l, pW3h, pW3l, pHh, pHl,
                                      v, Xb, Xh, n4, vflag, eflag,
                                      ei, E, N, rowi, coli, deg, cnt,
                                      c1, c2, c3, c4, c5, c6);

  // scan (+dis) and place
  k_scan<<<1, 1024, 0, stream>>>(cnt, colPtr, cursor, deg, dis, N);
  k_place<<<(E + 255) / 256, 256, 0, stream>>>(rowi, coli, dis, cursor, edges, E);

  const int gM = (N + 63) / 64;
  const int gP = (N + 3) / 4;

  // layer 1: Fi=128 -> Fo=128, X -> Y
  k_prop128<<<gP, 256, 0, stream>>>(Xb, nullptr, t1b, t1h, colPtr, edges, N, 1.f, 0.f);
  k_prop128<<<gP, 256, 0, stream>>>(t1b, Xb, nullptr, t2h, colPtr, edges, N, 2.f, -1.f);
  k_gemm_mfma<<<dim3(2, gM), 256, 0, stream>>>(Xh, t1h, t2h, pW1h, pW1l,
                                               b1, b1, vflag, N, 128, 3, 128,
                                               Yb, Yh, nullptr, nullptr, 1, 0);

  // layer 2: Fi=128 -> Fo=256, Y -> X
  k_prop128<<<gP, 256, 0, stream>>>(Yb, nullptr, t1b, t1h, colPtr, edges, N, 1.f, 0.f);
  k_prop128<<<gP, 256, 0, stream>>>(t1b, Yb, nullptr, t2h, colPtr, edges, N, 2.f, -1.f);
  k_gemm_mfma<<<dim3(4, gM), 256, 0, stream>>>(Yh, t1h, t2h, pW2h, pW2l,
                                               b2, b2, vflag, N, 128, 3, 256,
                                               Xb, Xh, nullptr, nullptr, 1, 0);

  // layer 3: Fi=256 -> Fo=512, X -> Y (hi pack only)
  k_prop256<<<gP, 256, 0, stream>>>(Xb, nullptr, t1b, t1h, colPtr, edges, N, 1.f, 0.f);
  k_prop256<<<gP, 256, 0, stream>>>(t1b, Xb, nullptr, t2h, colPtr, edges, N, 2.f, -1.f);
  k_gemm_mfma<<<dim3(8, gM), 256, 0, stream>>>(Xh, t1h, t2h, pW3h, pW3l,
                                               b3, b3, vflag, N, 256, 3, 512,
                                               nullptr, Yh, nullptr, nullptr, 1, 0);

  // fused heads: hi-only x3 operand
  k_gemm_mfma<<<dim3(8, gM), 256, 0, stream>>>(Yh, nullptr, nullptr, pHh, pHl,
                                               bmu, bstd, vflag, N, 512, 1, 512,
                                               nullptr, nullptr,
                                               (u16*)d_out, (float*)d_out, 0, 1);
}